// Round 1
// baseline (17450.533 us; speedup 1.0000x reference)
//
#include <hip/hip_runtime.h>
#include <math.h>

// Problem constants
#define Qn 2048
#define Nn 64
#define Sn 128
#define An 4
#define En 128
#define TASKW 576  // N + 4*S

// ---------------------------------------------------------------------------
// Threefry-2x32 (20 rounds), matches JAX's threefry2x32_p exactly.
// ---------------------------------------------------------------------------
__device__ __forceinline__ void threefry2x32(unsigned k0, unsigned k1,
                                             unsigned x0, unsigned x1,
                                             unsigned& o0, unsigned& o1) {
  unsigned ks2 = k0 ^ k1 ^ 0x1BD11BDAu;
  x0 += k0; x1 += k1;
#define TFR(r) { x0 += x1; x1 = (x1 << (r)) | (x1 >> (32 - (r))); x1 ^= x0; }
  TFR(13) TFR(15) TFR(26) TFR(6)
  x0 += k1;  x1 += ks2 + 1u;
  TFR(17) TFR(29) TFR(16) TFR(24)
  x0 += ks2; x1 += k0 + 2u;
  TFR(13) TFR(15) TFR(26) TFR(6)
  x0 += k0;  x1 += k1 + 3u;
  TFR(17) TFR(29) TFR(16) TFR(24)
  x0 += k1;  x1 += ks2 + 4u;
  TFR(13) TFR(15) TFR(26) TFR(6)
  x0 += ks2; x1 += k0 + 5u;
#undef TFR
  o0 = x0; o1 = x1;
}

__device__ __forceinline__ float silu_f(float x) {
  return x / (1.0f + expf(-x));
}

// ---------------------------------------------------------------------------
// Setup: M = w_node2 @ w_ser2^T (fold of ser MLP layer-2 through tne),
// dvec/m2/c0 bias folds, and keys = jax.random.split(key(1), 64)
// under threefry_partitionable semantics: key t = threefry((0,1),(0,t)).
// ---------------------------------------------------------------------------
__global__ void setup_kernel(const float* __restrict__ w_node2,
                             const float* __restrict__ b_node2,
                             const float* __restrict__ w_ser2,
                             const float* __restrict__ b_ser2,
                             float* __restrict__ Mbuf, float* __restrict__ dvec,
                             float* __restrict__ m2v, float* __restrict__ c0p,
                             unsigned* __restrict__ keys) {
  const int b = blockIdx.x, t = threadIdx.x;
  if (b < 128) {
    float acc = 0.0f;
    for (int e = 0; e < 128; ++e)
      acc = fmaf(w_node2[b * 128 + e], w_ser2[t * 128 + e], acc);
    Mbuf[b * 128 + t] = acc;
    if (t == 0) {
      float a2 = 0.0f;
      for (int e = 0; e < 128; ++e)
        a2 = fmaf(w_node2[b * 128 + e], b_ser2[e], a2);
      m2v[b] = a2;
    }
  } else if (b == 128) {
    float acc = 0.0f;
    for (int e = 0; e < 128; ++e)
      acc = fmaf(b_node2[e], w_ser2[t * 128 + e], acc);
    dvec[t] = acc;
    if (t == 0) {
      float c = 0.0f;
      for (int e = 0; e < 128; ++e) c = fmaf(b_node2[e], b_ser2[e], c);
      c0p[0] = c;
    }
  } else {
    if (t < 64) {
      unsigned o0, o1;
      threefry2x32(0u, 1u, 0u, (unsigned)t, o0, o1);
      keys[2 * t + 0] = o0;
      keys[2 * t + 1] = o1;
    }
  }
}

// ---------------------------------------------------------------------------
// K1: node_emb = silu(concat(tasks[:,:, :64], cons) @ w1 + b1) @ w2 + b2
// One workgroup per q; weight columns live in registers (per-thread column).
// ---------------------------------------------------------------------------
__global__ __launch_bounds__(256, 2)
void init_mlp_kernel(const float* __restrict__ tasks,
                     const float* __restrict__ cons,
                     const float* __restrict__ w1, const float* __restrict__ b1,
                     const float* __restrict__ w2, const float* __restrict__ b2,
                     float* __restrict__ node_emb) {
  const int q = blockIdx.x, tid = threadIdx.x;
  const int lane = tid & 127, half = tid >> 7;
  __shared__ float xr[2][68];
  __shared__ float sgb[2][128];
  float w1r[68], w2r[128];
#pragma unroll
  for (int i = 0; i < 68; ++i) w1r[i] = w1[i * 128 + lane];
#pragma unroll
  for (int j = 0; j < 128; ++j) w2r[j] = w2[j * 128 + lane];
  const float bb1 = b1[lane], bb2 = b2[lane];
  for (int r = 0; r < 64; r += 2) {
    if (tid < 136) {
      const int rr = tid / 68, j = tid - rr * 68;
      xr[rr][j] = (j < 64) ? tasks[(q * 64 + r + rr) * TASKW + j]
                           : cons[q * 4 + (j - 64)];
    }
    __syncthreads();
    float g = 0.0f;
#pragma unroll
    for (int i = 0; i < 68; ++i) g = fmaf(xr[half][i], w1r[i], g);
    g += bb1;
    sgb[half][lane] = silu_f(g);
    __syncthreads();
    float o = 0.0f;
#pragma unroll
    for (int j = 0; j < 128; ++j) o = fmaf(sgb[half][j], w2r[j], o);
    node_emb[(q * 64 + r + half) * 128 + lane] = o + bb2;
    __syncthreads();
  }
}

// ---------------------------------------------------------------------------
// K2: MHA heads. Per q: qh/kh/vh = relu(x@W+b) head slices, scores/4,
// softmax, y = attn@vh written to y_out (the nodes_emb buffer as scratch).
// ---------------------------------------------------------------------------
__global__ __launch_bounds__(256, 2)
void mha_kernel(const float* __restrict__ node_emb,
                const float* __restrict__ wq, const float* __restrict__ bq,
                const float* __restrict__ wk, const float* __restrict__ bk,
                const float* __restrict__ wv, const float* __restrict__ bv,
                float* __restrict__ y_out) {
  const int q = blockIdx.x, tid = threadIdx.x;
  __shared__ float xs[64][129];
  __shared__ float qh[64][17], kh[64][17], vh[64][17];
  __shared__ float at[64][65];
  for (int idx = tid; idx < 64 * 128; idx += 256) {
    const int n = idx >> 7, e = idx & 127;
    xs[n][e] = node_emb[(q * 64 + n) * 128 + e];
  }
  __syncthreads();
  const int dd = tid & 15, ngrp = tid >> 4;
  for (int hd = 0; hd < 8; ++hd) {
    const int col = hd * 16 + dd;
    {
      float wcol[128];
#pragma unroll
      for (int i = 0; i < 128; ++i) wcol[i] = wq[i * 128 + col];
      const float bb = bq[col];
      for (int k = 0; k < 4; ++k) {
        const int n = ngrp + 16 * k;
        float acc = 0.0f;
#pragma unroll
        for (int i = 0; i < 128; ++i) acc = fmaf(xs[n][i], wcol[i], acc);
        qh[n][dd] = fmaxf(acc + bb, 0.0f);
      }
    }
    {
      float wcol[128];
#pragma unroll
      for (int i = 0; i < 128; ++i) wcol[i] = wk[i * 128 + col];
      const float bb = bk[col];
      for (int k = 0; k < 4; ++k) {
        const int n = ngrp + 16 * k;
        float acc = 0.0f;
#pragma unroll
        for (int i = 0; i < 128; ++i) acc = fmaf(xs[n][i], wcol[i], acc);
        kh[n][dd] = fmaxf(acc + bb, 0.0f);
      }
    }
    {
      float wcol[128];
#pragma unroll
      for (int i = 0; i < 128; ++i) wcol[i] = wv[i * 128 + col];
      const float bb = bv[col];
      for (int k = 0; k < 4; ++k) {
        const int n = ngrp + 16 * k;
        float acc = 0.0f;
#pragma unroll
        for (int i = 0; i < 128; ++i) acc = fmaf(xs[n][i], wcol[i], acc);
        vh[n][dd] = fmaxf(acc + bb, 0.0f);
      }
    }
    __syncthreads();
    {
      const int n = tid >> 2, mg = tid & 3;
      for (int j = 0; j < 16; ++j) {
        const int m = mg * 16 + j;
        float acc = 0.0f;
#pragma unroll
        for (int d2 = 0; d2 < 16; ++d2) acc = fmaf(qh[n][d2], kh[m][d2], acc);
        at[n][m] = acc * 0.25f;  // exact: / sqrt(16)
      }
    }
    __syncthreads();
    if (tid < 64) {
      float mxv = at[tid][0];
      for (int m = 1; m < 64; ++m) mxv = fmaxf(mxv, at[tid][m]);
      float sum = 0.0f;
      for (int m = 0; m < 64; ++m) sum += expf(at[tid][m] - mxv);
      for (int m = 0; m < 64; ++m) at[tid][m] = expf(at[tid][m] - mxv) / sum;
    }
    __syncthreads();
    for (int k = 0; k < 4; ++k) {
      const int n = ngrp + 16 * k;
      float acc = 0.0f;
#pragma unroll
      for (int m = 0; m < 64; ++m) acc = fmaf(at[n][m], vh[m][dd], acc);
      y_out[(q * 64 + n) * 128 + col] = acc;
    }
    __syncthreads();
  }
}

// ---------------------------------------------------------------------------
// K3: nodes_emb = relu(y @ wo + bo) + node_emb  (in-place over y buffer)
// ---------------------------------------------------------------------------
__global__ __launch_bounds__(256, 2)
void outproj_kernel(const float* __restrict__ node_emb,
                    const float* __restrict__ wo, const float* __restrict__ bo,
                    float* __restrict__ nodes_emb) {
  const int q = blockIdx.x, tid = threadIdx.x;
  const int lane = tid & 127, half = tid >> 7;
  __shared__ float yr[2][128];
  __shared__ float xr[2][128];
  float wor[128];
#pragma unroll
  for (int j = 0; j < 128; ++j) wor[j] = wo[j * 128 + lane];
  const float bb = bo[lane];
  for (int r = 0; r < 64; r += 2) {
    yr[half][lane] = nodes_emb[(q * 64 + r + half) * 128 + lane];
    xr[half][lane] = node_emb[(q * 64 + r + half) * 128 + lane];
    __syncthreads();
    float o = 0.0f;
#pragma unroll
    for (int j = 0; j < 128; ++j) o = fmaf(yr[half][j], wor[j], o);
    o = fmaxf(o + bb, 0.0f) + xr[half][lane];
    __syncthreads();
    nodes_emb[(q * 64 + r + half) * 128 + lane] = o;
  }
}

// ---------------------------------------------------------------------------
// K4: the full 64-step scan, one workgroup per q (scan is per-q independent).
// w_node1 columns + M columns in registers; everything else small LDS.
// ---------------------------------------------------------------------------
__global__ __launch_bounds__(256, 2)
void scan_kernel(const float* __restrict__ tasks, const int* __restrict__ masks,
                 const int* __restrict__ topologicals,
                 const float* __restrict__ w_node1,
                 const float* __restrict__ b_node1,
                 const float* __restrict__ w_ser1,
                 const float* __restrict__ b_ser1,
                 const float* __restrict__ nodes_emb,
                 const float* __restrict__ Mbuf, const float* __restrict__ dvec,
                 const float* __restrict__ m2v, const float* __restrict__ c0p,
                 const unsigned* __restrict__ keys, float* __restrict__ out) {
  const int q = blockIdx.x, tid = threadIdx.x;
  const int lane = tid & 127, half = tid >> 7;

  __shared__ float task_s[TASKW];
  __shared__ float node_e[128];
  __shared__ float sg[128];
  __shared__ float uu[128];
  __shared__ float logit_s[128];
  __shared__ float red[256];
  __shared__ float qos_s[64 * 4];
  __shared__ float ridx_s[64], rprob_s[64];
  __shared__ float ws1[4 * 128];
  __shared__ float bs1[128];
  __shared__ float dvs[128], m2s[128];
  __shared__ float scal[8];  // 0:rt 1:ava 2:tp 3:rel 4:c 5:mx 6:sumexp
  __shared__ int mask_s[128];
  __shared__ int sidx_s;
  __shared__ unsigned keys_s[128];

  float w1r[66];
#pragma unroll
  for (int j = 0; j < 66; ++j) w1r[j] = w_node1[(half * 66 + j) * 128 + lane];
  float Mr[64];
#pragma unroll
  for (int j = 0; j < 64; ++j) Mr[j] = Mbuf[(half * 64 + j) * 128 + lane];

  for (int i = tid; i < 512; i += 256) ws1[i] = w_ser1[i];
  if (tid < 128) {
    bs1[tid] = b_ser1[tid];
    dvs[tid] = dvec[tid];
    m2s[tid] = m2v[tid];
    keys_s[tid] = keys[tid];
  }
  if (tid < 64) {
    qos_s[tid * 4 + 0] = 3.0f;
    qos_s[tid * 4 + 1] = 1.0f;
    qos_s[tid * 4 + 2] = 0.0f;
    qos_s[tid * 4 + 3] = 1.0f;
    ridx_s[tid] = 0.0f;
    rprob_s[tid] = 0.0f;
  }
  if (tid == 0) { scal[1] = 1.0f; scal[2] = 3.0f; scal[3] = 1.0f; }
  const float b1l = b_node1[lane];
  const float c0 = c0p[0];
  __syncthreads();

  for (int t = 0; t < 64; ++t) {
    const int topo = topologicals[q * 64 + (63 - t)];  // topo_seq reversal
    for (int j = tid; j < TASKW; j += 256)
      task_s[j] = tasks[(q * 64 + topo) * TASKW + j];
    if (tid < 128) {
      node_e[tid] = nodes_emb[(q * 64 + topo) * 128 + tid];
      mask_s[tid] = masks[(q * 64 + topo) * 128 + tid];
    }
    __syncthreads();

    // response_time = max_n(workflow[n] * qos[n,0])
    if (tid < 64) {
      float p = task_s[tid] * qos_s[tid * 4];
#pragma unroll
      for (int o = 32; o > 0; o >>= 1) p = fmaxf(p, __shfl_xor(p, o, 64));
      if (tid == 0) scal[0] = p;
    }
    __syncthreads();
    const float rt = scal[0], ava = scal[1], tp = scal[2], rel = scal[3];

    // g = concat(node_e, [rt,ava,tp,rel]) @ w_node1 (half-split over input)
    {
      float acc = 0.0f;
      if (half == 0) {
#pragma unroll
        for (int j = 0; j < 66; ++j) acc = fmaf(node_e[j], w1r[j], acc);
      } else {
#pragma unroll
        for (int j = 0; j < 62; ++j) acc = fmaf(node_e[66 + j], w1r[j], acc);
        acc = fmaf(rt, w1r[62], acc);
        acc = fmaf(ava, w1r[63], acc);
        acc = fmaf(tp, w1r[64], acc);
        acc = fmaf(rel, w1r[65], acc);
      }
      red[tid] = acc;
    }
    __syncthreads();
    if (tid < 128) {
      const float g = red[tid] + red[tid + 128] + b1l;
      sg[tid] = silu_f(g);
    }
    __syncthreads();

    // u = silu(g) @ M + d ;  c = silu(g) . m2 + c0
    {
      float acc = 0.0f;
#pragma unroll
      for (int j = 0; j < 64; ++j) acc = fmaf(sg[half * 64 + j], Mr[j], acc);
      red[tid] = acc;
    }
    __syncthreads();
    if (tid < 128) uu[tid] = red[tid] + red[tid + 128] + dvs[tid];
    if (tid < 64) {
      float cp = sg[tid] * m2s[tid] + sg[tid + 64] * m2s[tid + 64];
#pragma unroll
      for (int o = 32; o > 0; o >>= 1) cp += __shfl_xor(cp, o, 64);
      if (tid == 0) scal[4] = cp + c0;
    }
    __syncthreads();
    const float cc = scal[4];

    // logits[s] = sum_h silu(serv[s]@w_ser1 + b_ser1)[h] * u[h] + c
    {
      const int s = lane;
      const float s0 = task_s[64 + s * 4 + 0];
      const float s1 = task_s[64 + s * 4 + 1];
      const float s2 = task_s[64 + s * 4 + 2];
      const float s3 = task_s[64 + s * 4 + 3];
      float acc = 0.0f;
      const int hb = half * 64;
#pragma unroll 8
      for (int j = 0; j < 64; ++j) {
        const int h = hb + j;
        float h1 = s0 * ws1[h];
        h1 = fmaf(s1, ws1[128 + h], h1);
        h1 = fmaf(s2, ws1[256 + h], h1);
        h1 = fmaf(s3, ws1[384 + h], h1);
        h1 += bs1[h];
        acc = fmaf(silu_f(h1), uu[h], acc);
      }
      red[tid] = acc;
    }
    __syncthreads();
    if (tid < 128) {
      float l = red[tid] + red[tid + 128] + cc;
      if (mask_s[tid] == 0) l = -1000000000.0f;
      logit_s[tid] = l;
      // gumbel: partitionable threefry, counter (0, q*128+s), bits = o0^o1
      unsigned o0, o1;
      threefry2x32(keys_s[2 * t], keys_s[2 * t + 1], 0u,
                   (unsigned)(q * 128 + tid), o0, o1);
      const unsigned bits = o0 ^ o1;
      const float f = __uint_as_float((bits >> 9) | 0x3f800000u) - 1.0f;
      const float u = (f > 0.0f) ? f : 1.17549435e-38f;
      const float gmb = -logf(-logf(u));
      red[tid] = l + gmb;
    }
    __syncthreads();
    // wave0: argmax(gumbel+logits); wave1: max(logits)
    if (tid < 64) {
      float z = red[tid];
      int zi = tid;
      const float z2 = red[tid + 64];
      if (z2 > z) { z = z2; zi = tid + 64; }
#pragma unroll
      for (int o = 32; o > 0; o >>= 1) {
        const float zo = __shfl_xor(z, o, 64);
        const int io = __shfl_xor(zi, o, 64);
        if (zo > z || (zo == z && io < zi)) { z = zo; zi = io; }
      }
      if (tid == 0) sidx_s = zi;
    } else if (tid < 128) {
      const int l2 = tid - 64;
      float mx = fmaxf(logit_s[l2], logit_s[l2 + 64]);
#pragma unroll
      for (int o = 32; o > 0; o >>= 1) mx = fmaxf(mx, __shfl_xor(mx, o, 64));
      if (l2 == 0) scal[5] = mx;
    }
    __syncthreads();
    const float mx = scal[5];
    if (tid < 64) {
      float e = expf(logit_s[tid] - mx) + expf(logit_s[tid + 64] - mx);
#pragma unroll
      for (int o = 32; o > 0; o >>= 1) e += __shfl_xor(e, o, 64);
      if (tid == 0) scal[6] = e;
    }
    __syncthreads();
    if (tid == 0) {
      const int si = sidx_s;
      const float prob = expf(logit_s[si] - mx) / scal[6];
      const float srt = task_s[64 + si * 4 + 0];
      const float sava = task_s[64 + si * 4 + 1];
      const float stp = task_s[64 + si * 4 + 2];
      const float srel = task_s[64 + si * 4 + 3];
      const float nava = sava * ava;
      const float ntp = fminf(stp, tp);
      const float nrel = srel * rel;
      qos_s[topo * 4 + 0] = srt + rt;
      qos_s[topo * 4 + 1] = nava;
      qos_s[topo * 4 + 2] = ntp;
      qos_s[topo * 4 + 3] = nrel;
      scal[1] = nava;
      scal[2] = ntp;
      scal[3] = nrel;
      ridx_s[topo] += (float)si;
      rprob_s[topo] += prob;
    }
    __syncthreads();
  }
  if (tid < 64) {
    out[q * 64 + tid] = ridx_s[tid];                 // output 0: ridx (as f32)
    out[Qn * Nn + q * 64 + tid] = rprob_s[tid];      // output 1: rprob
  }
}

// ---------------------------------------------------------------------------
extern "C" void kernel_launch(void* const* d_in, const int* in_sizes, int n_in,
                              void* d_out, int out_size, void* d_ws,
                              size_t ws_size, hipStream_t stream) {
  const float* tasks = (const float*)d_in[0];
  const float* constraints = (const float*)d_in[1];
  const int* masks = (const int*)d_in[2];
  const int* topologicals = (const int*)d_in[3];
  const float* w_init1 = (const float*)d_in[4];
  const float* b_init1 = (const float*)d_in[5];
  const float* w_init2 = (const float*)d_in[6];
  const float* b_init2 = (const float*)d_in[7];
  const float* wq = (const float*)d_in[8];
  const float* bq = (const float*)d_in[9];
  const float* wk = (const float*)d_in[10];
  const float* bk = (const float*)d_in[11];
  const float* wv = (const float*)d_in[12];
  const float* bv = (const float*)d_in[13];
  const float* wo = (const float*)d_in[14];
  const float* bo = (const float*)d_in[15];
  const float* w_node1 = (const float*)d_in[16];
  const float* b_node1 = (const float*)d_in[17];
  const float* w_node2 = (const float*)d_in[18];
  const float* b_node2 = (const float*)d_in[19];
  const float* w_ser1 = (const float*)d_in[20];
  const float* b_ser1 = (const float*)d_in[21];
  const float* w_ser2 = (const float*)d_in[22];
  const float* b_ser2 = (const float*)d_in[23];

  float* ws = (float*)d_ws;
  float* node_emb = ws;                                   // Q*N*E
  float* nodes_emb = node_emb + (size_t)Qn * Nn * En;     // Q*N*E (y scratch, then final)
  float* Mbuf = nodes_emb + (size_t)Qn * Nn * En;         // 128*128
  float* dvec = Mbuf + 128 * 128;
  float* m2v = dvec + 128;
  float* c0p = m2v + 128;
  unsigned* keys = (unsigned*)(c0p + 4);                  // 128 u32

  setup_kernel<<<130, 128, 0, stream>>>(w_node2, b_node2, w_ser2, b_ser2, Mbuf,
                                        dvec, m2v, c0p, keys);
  init_mlp_kernel<<<Qn, 256, 0, stream>>>(tasks, constraints, w_init1, b_init1,
                                          w_init2, b_init2, node_emb);
  mha_kernel<<<Qn, 256, 0, stream>>>(node_emb, wq, bq, wk, bk, wv, bv,
                                     nodes_emb);
  outproj_kernel<<<Qn, 256, 0, stream>>>(node_emb, wo, bo, nodes_emb);
  scan_kernel<<<Qn, 256, 0, stream>>>(tasks, masks, topologicals, w_node1,
                                      b_node1, w_ser1, b_ser1, nodes_emb, Mbuf,
                                      dvec, m2v, c0p, keys, (float*)d_out);
}

// Round 2
// 3845.750 us; speedup vs baseline: 4.5376x; 4.5376x over previous
//
#include <hip/hip_runtime.h>
#include <math.h>

// Problem constants
#define Qn 2048
#define Nn 64
#define Sn 128
#define An 4
#define En 128
#define TASKW 576  // N + 4*S

// ---------------------------------------------------------------------------
// Threefry-2x32 (20 rounds), matches JAX's threefry2x32_p exactly.
// ---------------------------------------------------------------------------
__device__ __forceinline__ void threefry2x32(unsigned k0, unsigned k1,
                                             unsigned x0, unsigned x1,
                                             unsigned& o0, unsigned& o1) {
  unsigned ks2 = k0 ^ k1 ^ 0x1BD11BDAu;
  x0 += k0; x1 += k1;
#define TFR(r) { x0 += x1; x1 = (x1 << (r)) | (x1 >> (32 - (r))); x1 ^= x0; }
  TFR(13) TFR(15) TFR(26) TFR(6)
  x0 += k1;  x1 += ks2 + 1u;
  TFR(17) TFR(29) TFR(16) TFR(24)
  x0 += ks2; x1 += k0 + 2u;
  TFR(13) TFR(15) TFR(26) TFR(6)
  x0 += k0;  x1 += k1 + 3u;
  TFR(17) TFR(29) TFR(16) TFR(24)
  x0 += k1;  x1 += ks2 + 4u;
  TFR(13) TFR(15) TFR(26) TFR(6)
  x0 += ks2; x1 += k0 + 5u;
#undef TFR
  o0 = x0; o1 = x1;
}

__device__ __forceinline__ float silu_f(float x) {
  return x / (1.0f + expf(-x));
}

// ---------------------------------------------------------------------------
// Setup: M = w_node2 @ w_ser2^T, bias folds, and PRNG keys
// keys = jax.random.split(key(1), 64): key t = threefry((0,1),(0,t)).
// ---------------------------------------------------------------------------
__global__ void setup_kernel(const float* __restrict__ w_node2,
                             const float* __restrict__ b_node2,
                             const float* __restrict__ w_ser2,
                             const float* __restrict__ b_ser2,
                             float* __restrict__ Mbuf, float* __restrict__ dvec,
                             float* __restrict__ m2v, float* __restrict__ c0p,
                             unsigned* __restrict__ keys) {
  const int b = blockIdx.x, t = threadIdx.x;
  if (b < 128) {
    float acc = 0.0f;
    for (int e = 0; e < 128; ++e)
      acc = fmaf(w_node2[b * 128 + e], w_ser2[t * 128 + e], acc);
    Mbuf[b * 128 + t] = acc;
    if (t == 0) {
      float a2 = 0.0f;
      for (int e = 0; e < 128; ++e)
        a2 = fmaf(w_node2[b * 128 + e], b_ser2[e], a2);
      m2v[b] = a2;
    }
  } else if (b == 128) {
    float acc = 0.0f;
    for (int e = 0; e < 128; ++e)
      acc = fmaf(b_node2[e], w_ser2[t * 128 + e], acc);
    dvec[t] = acc;
    if (t == 0) {
      float c = 0.0f;
      for (int e = 0; e < 128; ++e) c = fmaf(b_node2[e], b_ser2[e], c);
      c0p[0] = c;
    }
  } else {
    if (t < 64) {
      unsigned o0, o1;
      threefry2x32(0u, 1u, 0u, (unsigned)t, o0, o1);
      keys[2 * t + 0] = o0;
      keys[2 * t + 1] = o1;
    }
  }
}

// ---------------------------------------------------------------------------
// K1: node_emb = silu(concat(tasks[:,:, :64], cons) @ w1 + b1) @ w2 + b2
// ---------------------------------------------------------------------------
__global__ __launch_bounds__(256, 2)
void init_mlp_kernel(const float* __restrict__ tasks,
                     const float* __restrict__ cons,
                     const float* __restrict__ w1, const float* __restrict__ b1,
                     const float* __restrict__ w2, const float* __restrict__ b2,
                     float* __restrict__ node_emb) {
  const int q = blockIdx.x, tid = threadIdx.x;
  const int lane = tid & 127, half = tid >> 7;
  __shared__ float xr[2][68];
  __shared__ float sgb[2][128];
  float w1r[68], w2r[128];
#pragma unroll
  for (int i = 0; i < 68; ++i) w1r[i] = w1[i * 128 + lane];
#pragma unroll
  for (int j = 0; j < 128; ++j) w2r[j] = w2[j * 128 + lane];
  const float bb1 = b1[lane], bb2 = b2[lane];
  for (int r = 0; r < 64; r += 2) {
    if (tid < 136) {
      const int rr = tid / 68, j = tid - rr * 68;
      xr[rr][j] = (j < 64) ? tasks[(q * 64 + r + rr) * TASKW + j]
                           : cons[q * 4 + (j - 64)];
    }
    __syncthreads();
    float g = 0.0f;
#pragma unroll
    for (int i = 0; i < 68; ++i) g = fmaf(xr[half][i], w1r[i], g);
    g += bb1;
    sgb[half][lane] = silu_f(g);
    __syncthreads();
    float o = 0.0f;
#pragma unroll
    for (int j = 0; j < 128; ++j) o = fmaf(sgb[half][j], w2r[j], o);
    node_emb[(q * 64 + r + half) * 128 + lane] = o + bb2;
    __syncthreads();
  }
}

// ---------------------------------------------------------------------------
// K2: fused MHA (QKV + scores + softmax + AV), no register arrays, all LDS.
// One block per q. LDS ~70KB -> 2 blocks/CU. Weight slices re-read from L2.
// ---------------------------------------------------------------------------
__global__ __launch_bounds__(256, 2)
void mha_kernel(const float* __restrict__ node_emb,
                const float* __restrict__ wq, const float* __restrict__ bq,
                const float* __restrict__ wk, const float* __restrict__ bk,
                const float* __restrict__ wv, const float* __restrict__ bv,
                float* __restrict__ y_out) {
  const int q = blockIdx.x, tid = threadIdx.x;
  __shared__ float xs[64][130];
  __shared__ float qh[64][18];
  __shared__ float kh[64][18];
  __shared__ float vt[16][66];
  __shared__ float pool[3 * 16 * 130];  // wht[3][16][130] U at[64][66]
  float (*wht)[16][130] = (float (*)[16][130])pool;
  float (*at)[66] = (float (*)[66])pool;

  for (int idx = tid; idx < 64 * 128; idx += 256) {
    const int n = idx >> 7, e = idx & 127;
    xs[n][e] = node_emb[(q * 64 + n) * 128 + e];
  }
  __syncthreads();

  const int d16 = tid >> 4;  // 0..15
  const int ng = tid & 15;   // 0..15

  for (int hd = 0; hd < 8; ++hd) {
    // ---- load transposed weight slices for this head into LDS ----
    for (int idx = tid; idx < 3 * 128 * 16; idx += 256) {
      const int m = idx >> 11, k = (idx >> 4) & 127, d = idx & 15;
      const float* W = (m == 0) ? wq : (m == 1) ? wk : wv;
      wht[m][d][k] = W[k * 128 + hd * 16 + d];
    }
    __syncthreads();

    // ---- QKV projection for this head: thread = (col d16, row-group ng) ----
    {
      const float bqv = bq[hd * 16 + d16];
      const float bkv = bk[hd * 16 + d16];
      const float bvv = bv[hd * 16 + d16];
      const float2* wq2 = (const float2*)&wht[0][d16][0];
      const float2* wk2 = (const float2*)&wht[1][d16][0];
      const float2* wv2 = (const float2*)&wht[2][d16][0];
      const float2* xr0 = (const float2*)&xs[ng][0];
      const float2* xr1 = (const float2*)&xs[ng + 16][0];
      const float2* xr2 = (const float2*)&xs[ng + 32][0];
      const float2* xr3 = (const float2*)&xs[ng + 48][0];
      float aq0 = 0, aq1 = 0, aq2 = 0, aq3 = 0;
      float ak0 = 0, ak1 = 0, ak2 = 0, ak3 = 0;
      float av0 = 0, av1 = 0, av2 = 0, av3 = 0;
#pragma unroll 8
      for (int kk = 0; kk < 64; ++kk) {
        const float2 wqv = wq2[kk], wkv = wk2[kk], wvv = wv2[kk];
        const float2 x0 = xr0[kk], x1 = xr1[kk], x2 = xr2[kk], x3 = xr3[kk];
        aq0 = fmaf(x0.y, wqv.y, fmaf(x0.x, wqv.x, aq0));
        aq1 = fmaf(x1.y, wqv.y, fmaf(x1.x, wqv.x, aq1));
        aq2 = fmaf(x2.y, wqv.y, fmaf(x2.x, wqv.x, aq2));
        aq3 = fmaf(x3.y, wqv.y, fmaf(x3.x, wqv.x, aq3));
        ak0 = fmaf(x0.y, wkv.y, fmaf(x0.x, wkv.x, ak0));
        ak1 = fmaf(x1.y, wkv.y, fmaf(x1.x, wkv.x, ak1));
        ak2 = fmaf(x2.y, wkv.y, fmaf(x2.x, wkv.x, ak2));
        ak3 = fmaf(x3.y, wkv.y, fmaf(x3.x, wkv.x, ak3));
        av0 = fmaf(x0.y, wvv.y, fmaf(x0.x, wvv.x, av0));
        av1 = fmaf(x1.y, wvv.y, fmaf(x1.x, wvv.x, av1));
        av2 = fmaf(x2.y, wvv.y, fmaf(x2.x, wvv.x, av2));
        av3 = fmaf(x3.y, wvv.y, fmaf(x3.x, wvv.x, av3));
      }
      qh[ng][d16] = fmaxf(aq0 + bqv, 0.0f);
      qh[ng + 16][d16] = fmaxf(aq1 + bqv, 0.0f);
      qh[ng + 32][d16] = fmaxf(aq2 + bqv, 0.0f);
      qh[ng + 48][d16] = fmaxf(aq3 + bqv, 0.0f);
      kh[ng][d16] = fmaxf(ak0 + bkv, 0.0f);
      kh[ng + 16][d16] = fmaxf(ak1 + bkv, 0.0f);
      kh[ng + 32][d16] = fmaxf(ak2 + bkv, 0.0f);
      kh[ng + 48][d16] = fmaxf(ak3 + bkv, 0.0f);
      vt[d16][ng] = fmaxf(av0 + bvv, 0.0f);
      vt[d16][ng + 16] = fmaxf(av1 + bvv, 0.0f);
      vt[d16][ng + 32] = fmaxf(av2 + bvv, 0.0f);
      vt[d16][ng + 48] = fmaxf(av3 + bvv, 0.0f);
    }
    __syncthreads();  // wht dead from here; pool becomes at[][]

    // ---- scores: at[n][m] = (qh[n].kh[m]) * 0.25 ----
    {
      const int n = tid >> 2, mg = tid & 3;
      float2 qv[8];
      const float2* qrow = (const float2*)&qh[n][0];
#pragma unroll
      for (int kk = 0; kk < 8; ++kk) qv[kk] = qrow[kk];
#pragma unroll 4
      for (int jj = 0; jj < 16; ++jj) {
        const int m = mg + 4 * jj;
        const float2* krow = (const float2*)&kh[m][0];
        float acc = 0.0f;
#pragma unroll
        for (int kk = 0; kk < 8; ++kk) {
          const float2 kv = krow[kk];
          acc = fmaf(qv[kk].y, kv.y, fmaf(qv[kk].x, kv.x, acc));
        }
        at[n][m] = acc * 0.25f;
      }
    }
    __syncthreads();

    // ---- softmax rows: 4 threads per row, shfl combine ----
    {
      const int r = tid >> 2, p = tid & 3;
      float mx = -1e30f;
#pragma unroll
      for (int t2 = 0; t2 < 16; ++t2) mx = fmaxf(mx, at[r][p * 16 + t2]);
      mx = fmaxf(mx, __shfl_xor(mx, 1, 64));
      mx = fmaxf(mx, __shfl_xor(mx, 2, 64));
      float s = 0.0f;
#pragma unroll
      for (int t2 = 0; t2 < 16; ++t2) {
        const float e = expf(at[r][p * 16 + t2] - mx);
        at[r][p * 16 + t2] = e;
        s += e;
      }
      s += __shfl_xor(s, 1, 64);
      s += __shfl_xor(s, 2, 64);
#pragma unroll
      for (int t2 = 0; t2 < 16; ++t2) at[r][p * 16 + t2] /= s;
    }
    __syncthreads();

    // ---- AV: y[n][hd*16+dd] = sum_m at[n][m] * v[m][dd] ----
    {
      const int dd = tid & 15, ngr = tid >> 4;
      const float2* vrow = (const float2*)&vt[dd][0];
      const float2* ar0 = (const float2*)&at[ngr][0];
      const float2* ar1 = (const float2*)&at[ngr + 16][0];
      const float2* ar2 = (const float2*)&at[ngr + 32][0];
      const float2* ar3 = (const float2*)&at[ngr + 48][0];
      float ac0 = 0, ac1 = 0, ac2 = 0, ac3 = 0;
#pragma unroll 8
      for (int kk = 0; kk < 32; ++kk) {
        const float2 vv = vrow[kk];
        const float2 a0 = ar0[kk], a1 = ar1[kk], a2 = ar2[kk], a3 = ar3[kk];
        ac0 = fmaf(a0.y, vv.y, fmaf(a0.x, vv.x, ac0));
        ac1 = fmaf(a1.y, vv.y, fmaf(a1.x, vv.x, ac1));
        ac2 = fmaf(a2.y, vv.y, fmaf(a2.x, vv.x, ac2));
        ac3 = fmaf(a3.y, vv.y, fmaf(a3.x, vv.x, ac3));
      }
      y_out[(q * 64 + ngr) * 128 + hd * 16 + dd] = ac0;
      y_out[(q * 64 + ngr + 16) * 128 + hd * 16 + dd] = ac1;
      y_out[(q * 64 + ngr + 32) * 128 + hd * 16 + dd] = ac2;
      y_out[(q * 64 + ngr + 48) * 128 + hd * 16 + dd] = ac3;
    }
    __syncthreads();  // before pool is overwritten next head
  }
}

// ---------------------------------------------------------------------------
// K3: nodes_emb = relu(y @ wo + bo) + node_emb   (LDS-tiled, no reg arrays)
// ---------------------------------------------------------------------------
__global__ __launch_bounds__(256, 4)
void outproj_kernel(const float* __restrict__ node_emb,
                    const float* __restrict__ wo, const float* __restrict__ bo,
                    float* __restrict__ nodes_emb) {
  const int q = blockIdx.x, tid = threadIdx.x;
  __shared__ float ys[64][130];
  __shared__ float wot[32][130];
  for (int idx = tid; idx < 64 * 128; idx += 256) {
    const int n = idx >> 7, e = idx & 127;
    ys[n][e] = nodes_emb[(q * 64 + n) * 128 + e];
  }
  const int cg = tid & 15, ngr = tid >> 4;
  for (int c0 = 0; c0 < 128; c0 += 32) {
    __syncthreads();  // ys complete / previous chunk's wot readers done
    for (int idx = tid; idx < 32 * 128; idx += 256) {
      const int k = idx >> 5, c = idx & 31;
      wot[c][k] = wo[k * 128 + c0 + c];
    }
    __syncthreads();
    const int c = c0 + 2 * cg;
    const float2* w0 = (const float2*)&wot[2 * cg][0];
    const float2* w1 = (const float2*)&wot[2 * cg + 1][0];
    const float2* yr0 = (const float2*)&ys[ngr][0];
    const float2* yr1 = (const float2*)&ys[ngr + 16][0];
    const float2* yr2 = (const float2*)&ys[ngr + 32][0];
    const float2* yr3 = (const float2*)&ys[ngr + 48][0];
    float a00 = 0, a01 = 0, a10 = 0, a11 = 0;
    float a20 = 0, a21 = 0, a30 = 0, a31 = 0;
#pragma unroll 8
    for (int kk = 0; kk < 64; ++kk) {
      const float2 wv0 = w0[kk], wv1 = w1[kk];
      const float2 x0 = yr0[kk], x1 = yr1[kk], x2 = yr2[kk], x3 = yr3[kk];
      a00 = fmaf(x0.y, wv0.y, fmaf(x0.x, wv0.x, a00));
      a01 = fmaf(x0.y, wv1.y, fmaf(x0.x, wv1.x, a01));
      a10 = fmaf(x1.y, wv0.y, fmaf(x1.x, wv0.x, a10));
      a11 = fmaf(x1.y, wv1.y, fmaf(x1.x, wv1.x, a11));
      a20 = fmaf(x2.y, wv0.y, fmaf(x2.x, wv0.x, a20));
      a21 = fmaf(x2.y, wv1.y, fmaf(x2.x, wv1.x, a21));
      a30 = fmaf(x3.y, wv0.y, fmaf(x3.x, wv0.x, a30));
      a31 = fmaf(x3.y, wv1.y, fmaf(x3.x, wv1.x, a31));
    }
    const float b0v = bo[c], b1v = bo[c + 1];
#define OUTP_EMIT(J, A0, A1)                                                  \
    {                                                                         \
      const int n = ngr + 16 * J;                                             \
      const float2 res = *(const float2*)&node_emb[(q * 64 + n) * 128 + c];   \
      float2 o;                                                               \
      o.x = fmaxf(A0 + b0v, 0.0f) + res.x;                                    \
      o.y = fmaxf(A1 + b1v, 0.0f) + res.y;                                    \
      *(float2*)&nodes_emb[(q * 64 + n) * 128 + c] = o;                       \
    }
    OUTP_EMIT(0, a00, a01)
    OUTP_EMIT(1, a10, a11)
    OUTP_EMIT(2, a20, a21)
    OUTP_EMIT(3, a30, a31)
#undef OUTP_EMIT
  }
}

// ---------------------------------------------------------------------------
// K4: the full 64-step scan, one workgroup per q.
// ---------------------------------------------------------------------------
__global__ __launch_bounds__(256, 2)
void scan_kernel(const float* __restrict__ tasks, const int* __restrict__ masks,
                 const int* __restrict__ topologicals,
                 const float* __restrict__ w_node1,
                 const float* __restrict__ b_node1,
                 const float* __restrict__ w_ser1,
                 const float* __restrict__ b_ser1,
                 const float* __restrict__ nodes_emb,
                 const float* __restrict__ Mbuf, const float* __restrict__ dvec,
                 const float* __restrict__ m2v, const float* __restrict__ c0p,
                 const unsigned* __restrict__ keys, float* __restrict__ out) {
  const int q = blockIdx.x, tid = threadIdx.x;
  const int lane = tid & 127, half = tid >> 7;

  __shared__ float task_s[TASKW];
  __shared__ float node_e[128];
  __shared__ float sg[128];
  __shared__ float uu[128];
  __shared__ float logit_s[128];
  __shared__ float red[256];
  __shared__ float qos_s[64 * 4];
  __shared__ float ridx_s[64], rprob_s[64];
  __shared__ float ws1[4 * 128];
  __shared__ float bs1[128];
  __shared__ float dvs[128], m2s[128];
  __shared__ float scal[8];  // 0:rt 1:ava 2:tp 3:rel 4:c 5:mx 6:sumexp
  __shared__ int mask_s[128];
  __shared__ int sidx_s;
  __shared__ unsigned keys_s[128];

  float w1r[66];
#pragma unroll
  for (int j = 0; j < 66; ++j) w1r[j] = w_node1[(half * 66 + j) * 128 + lane];
  float Mr[64];
#pragma unroll
  for (int j = 0; j < 64; ++j) Mr[j] = Mbuf[(half * 64 + j) * 128 + lane];

  for (int i = tid; i < 512; i += 256) ws1[i] = w_ser1[i];
  if (tid < 128) {
    bs1[tid] = b_ser1[tid];
    dvs[tid] = dvec[tid];
    m2s[tid] = m2v[tid];
    keys_s[tid] = keys[tid];
  }
  if (tid < 64) {
    qos_s[tid * 4 + 0] = 3.0f;
    qos_s[tid * 4 + 1] = 1.0f;
    qos_s[tid * 4 + 2] = 0.0f;
    qos_s[tid * 4 + 3] = 1.0f;
    ridx_s[tid] = 0.0f;
    rprob_s[tid] = 0.0f;
  }
  if (tid == 0) { scal[1] = 1.0f; scal[2] = 3.0f; scal[3] = 1.0f; }
  const float b1l = b_node1[lane];
  const float c0 = c0p[0];
  __syncthreads();

  for (int t = 0; t < 64; ++t) {
    const int topo = topologicals[q * 64 + (63 - t)];  // topo_seq reversal
    for (int j = tid; j < TASKW; j += 256)
      task_s[j] = tasks[(q * 64 + topo) * TASKW + j];
    if (tid < 128) {
      node_e[tid] = nodes_emb[(q * 64 + topo) * 128 + tid];
      mask_s[tid] = masks[(q * 64 + topo) * 128 + tid];
    }
    __syncthreads();

    // response_time = max_n(workflow[n] * qos[n,0])
    if (tid < 64) {
      float p = task_s[tid] * qos_s[tid * 4];
#pragma unroll
      for (int o = 32; o > 0; o >>= 1) p = fmaxf(p, __shfl_xor(p, o, 64));
      if (tid == 0) scal[0] = p;
    }
    __syncthreads();
    const float rt = scal[0], ava = scal[1], tp = scal[2], rel = scal[3];

    // g = concat(node_e, [rt,ava,tp,rel]) @ w_node1 (half-split over input)
    {
      float acc = 0.0f;
      if (half == 0) {
#pragma unroll
        for (int j = 0; j < 66; ++j) acc = fmaf(node_e[j], w1r[j], acc);
      } else {
#pragma unroll
        for (int j = 0; j < 62; ++j) acc = fmaf(node_e[66 + j], w1r[j], acc);
        acc = fmaf(rt, w1r[62], acc);
        acc = fmaf(ava, w1r[63], acc);
        acc = fmaf(tp, w1r[64], acc);
        acc = fmaf(rel, w1r[65], acc);
      }
      red[tid] = acc;
    }
    __syncthreads();
    if (tid < 128) {
      const float g = red[tid] + red[tid + 128] + b1l;
      sg[tid] = silu_f(g);
    }
    __syncthreads();

    // u = silu(g) @ M + d ;  c = silu(g) . m2 + c0
    {
      float acc = 0.0f;
#pragma unroll
      for (int j = 0; j < 64; ++j) acc = fmaf(sg[half * 64 + j], Mr[j], acc);
      red[tid] = acc;
    }
    __syncthreads();
    if (tid < 128) uu[tid] = red[tid] + red[tid + 128] + dvs[tid];
    if (tid < 64) {
      float cp = sg[tid] * m2s[tid] + sg[tid + 64] * m2s[tid + 64];
#pragma unroll
      for (int o = 32; o > 0; o >>= 1) cp += __shfl_xor(cp, o, 64);
      if (tid == 0) scal[4] = cp + c0;
    }
    __syncthreads();
    const float cc = scal[4];

    // logits[s] = sum_h silu(serv[s]@w_ser1 + b_ser1)[h] * u[h] + c
    {
      const int s = lane;
      const float s0 = task_s[64 + s * 4 + 0];
      const float s1 = task_s[64 + s * 4 + 1];
      const float s2 = task_s[64 + s * 4 + 2];
      const float s3 = task_s[64 + s * 4 + 3];
      float acc = 0.0f;
      const int hb = half * 64;
#pragma unroll 8
      for (int j = 0; j < 64; ++j) {
        const int h = hb + j;
        float h1 = s0 * ws1[h];
        h1 = fmaf(s1, ws1[128 + h], h1);
        h1 = fmaf(s2, ws1[256 + h], h1);
        h1 = fmaf(s3, ws1[384 + h], h1);
        h1 += bs1[h];
        acc = fmaf(silu_f(h1), uu[h], acc);
      }
      red[tid] = acc;
    }
    __syncthreads();
    if (tid < 128) {
      float l = red[tid] + red[tid + 128] + cc;
      if (mask_s[tid] == 0) l = -1000000000.0f;
      logit_s[tid] = l;
      // gumbel: partitionable threefry, counter (0, q*128+s), bits = o0^o1
      unsigned o0, o1;
      threefry2x32(keys_s[2 * t], keys_s[2 * t + 1], 0u,
                   (unsigned)(q * 128 + tid), o0, o1);
      const unsigned bits = o0 ^ o1;
      const float f = __uint_as_float((bits >> 9) | 0x3f800000u) - 1.0f;
      const float u = (f > 0.0f) ? f : 1.17549435e-38f;
      const float gmb = -logf(-logf(u));
      red[tid] = l + gmb;
    }
    __syncthreads();
    // wave0: argmax(gumbel+logits); wave1: max(logits)
    if (tid < 64) {
      float z = red[tid];
      int zi = tid;
      const float z2 = red[tid + 64];
      if (z2 > z) { z = z2; zi = tid + 64; }
#pragma unroll
      for (int o = 32; o > 0; o >>= 1) {
        const float zo = __shfl_xor(z, o, 64);
        const int io = __shfl_xor(zi, o, 64);
        if (zo > z || (zo == z && io < zi)) { z = zo; zi = io; }
      }
      if (tid == 0) sidx_s = zi;
    } else if (tid < 128) {
      const int l2 = tid - 64;
      float mx = fmaxf(logit_s[l2], logit_s[l2 + 64]);
#pragma unroll
      for (int o = 32; o > 0; o >>= 1) mx = fmaxf(mx, __shfl_xor(mx, o, 64));
      if (l2 == 0) scal[5] = mx;
    }
    __syncthreads();
    const float mx = scal[5];
    if (tid < 64) {
      float e = expf(logit_s[tid] - mx) + expf(logit_s[tid + 64] - mx);
#pragma unroll
      for (int o = 32; o > 0; o >>= 1) e += __shfl_xor(e, o, 64);
      if (tid == 0) scal[6] = e;
    }
    __syncthreads();
    if (tid == 0) {
      const int si = sidx_s;
      const float prob = expf(logit_s[si] - mx) / scal[6];
      const float srt = task_s[64 + si * 4 + 0];
      const float sava = task_s[64 + si * 4 + 1];
      const float stp = task_s[64 + si * 4 + 2];
      const float srel = task_s[64 + si * 4 + 3];
      const float nava = sava * ava;
      const float ntp = fminf(stp, tp);
      const float nrel = srel * rel;
      qos_s[topo * 4 + 0] = srt + rt;
      qos_s[topo * 4 + 1] = nava;
      qos_s[topo * 4 + 2] = ntp;
      qos_s[topo * 4 + 3] = nrel;
      scal[1] = nava;
      scal[2] = ntp;
      scal[3] = nrel;
      ridx_s[topo] += (float)si;
      rprob_s[topo] += prob;
    }
    __syncthreads();
  }
  if (tid < 64) {
    out[q * 64 + tid] = ridx_s[tid];
    out[Qn * Nn + q * 64 + tid] = rprob_s[tid];
  }
}

// ---------------------------------------------------------------------------
extern "C" void kernel_launch(void* const* d_in, const int* in_sizes, int n_in,
                              void* d_out, int out_size, void* d_ws,
                              size_t ws_size, hipStream_t stream) {
  const float* tasks = (const float*)d_in[0];
  const float* constraints = (const float*)d_in[1];
  const int* masks = (const int*)d_in[2];
  const int* topologicals = (const int*)d_in[3];
  const float* w_init1 = (const float*)d_in[4];
  const float* b_init1 = (const float*)d_in[5];
  const float* w_init2 = (const float*)d_in[6];
  const float* b_init2 = (const float*)d_in[7];
  const float* wq = (const float*)d_in[8];
  const float* bq = (const float*)d_in[9];
  const float* wk = (const float*)d_in[10];
  const float* bk = (const float*)d_in[11];
  const float* wv = (const float*)d_in[12];
  const float* bv = (const float*)d_in[13];
  const float* wo = (const float*)d_in[14];
  const float* bo = (const float*)d_in[15];
  const float* w_node1 = (const float*)d_in[16];
  const float* b_node1 = (const float*)d_in[17];
  const float* w_node2 = (const float*)d_in[18];
  const float* b_node2 = (const float*)d_in[19];
  const float* w_ser1 = (const float*)d_in[20];
  const float* b_ser1 = (const float*)d_in[21];
  const float* w_ser2 = (const float*)d_in[22];
  const float* b_ser2 = (const float*)d_in[23];

  float* ws = (float*)d_ws;
  float* node_emb = ws;                                // Q*N*E
  float* nodes_emb = node_emb + (size_t)Qn * Nn * En;  // Q*N*E (y, then final)
  float* Mbuf = nodes_emb + (size_t)Qn * Nn * En;      // 128*128
  float* dvec = Mbuf + 128 * 128;
  float* m2v = dvec + 128;
  float* c0p = m2v + 128;
  unsigned* keys = (unsigned*)(c0p + 4);               // 128 u32

  setup_kernel<<<130, 128, 0, stream>>>(w_node2, b_node2, w_ser2, b_ser2, Mbuf,
                                        dvec, m2v, c0p, keys);
  init_mlp_kernel<<<Qn, 256, 0, stream>>>(tasks, constraints, w_init1, b_init1,
                                          w_init2, b_init2, node_emb);
  mha_kernel<<<Qn, 256, 0, stream>>>(node_emb, wq, bq, wk, bk, wv, bv,
                                     nodes_emb);
  outproj_kernel<<<Qn, 256, 0, stream>>>(node_emb, wo, bo, nodes_emb);
  scan_kernel<<<Qn, 256, 0, stream>>>(tasks, masks, topologicals, w_node1,
                                      b_node1, w_ser1, b_ser1, nodes_emb, Mbuf,
                                      dvec, m2v, c0p, keys, (float*)d_out);
}

// Round 3
// 2927.729 us; speedup vs baseline: 5.9604x; 1.3136x over previous
//
#include <hip/hip_runtime.h>
#include <math.h>

// Problem constants
#define Qn 2048
#define Nn 64
#define Sn 128
#define An 4
#define En 128
#define TASKW 576  // N + 4*S
#define NEGV -1000000000.0f

// ---------------------------------------------------------------------------
// Threefry-2x32 (20 rounds), matches JAX's threefry2x32_p exactly.
// ---------------------------------------------------------------------------
__device__ __forceinline__ void threefry2x32(unsigned k0, unsigned k1,
                                             unsigned x0, unsigned x1,
                                             unsigned& o0, unsigned& o1) {
  unsigned ks2 = k0 ^ k1 ^ 0x1BD11BDAu;
  x0 += k0; x1 += k1;
#define TFR(r) { x0 += x1; x1 = (x1 << (r)) | (x1 >> (32 - (r))); x1 ^= x0; }
  TFR(13) TFR(15) TFR(26) TFR(6)
  x0 += k1;  x1 += ks2 + 1u;
  TFR(17) TFR(29) TFR(16) TFR(24)
  x0 += ks2; x1 += k0 + 2u;
  TFR(13) TFR(15) TFR(26) TFR(6)
  x0 += k0;  x1 += k1 + 3u;
  TFR(17) TFR(29) TFR(16) TFR(24)
  x0 += k1;  x1 += ks2 + 4u;
  TFR(13) TFR(15) TFR(26) TFR(6)
  x0 += ks2; x1 += k0 + 5u;
#undef TFR
  o0 = x0; o1 = x1;
}

__device__ __forceinline__ float silu_f(float x) {
  return x / (1.0f + expf(-x));
}

// Fast-math helpers (v_exp_f32 / v_log_f32 / v_rcp_f32; ~1 ulp)
__device__ __forceinline__ float fexp(float x) {
  return __builtin_amdgcn_exp2f(x * 1.44269504088896f);
}
__device__ __forceinline__ float fsilu(float x) {
  const float e = __builtin_amdgcn_exp2f(x * -1.44269504088896f);
  return x * __builtin_amdgcn_rcpf(1.0f + e);
}
__device__ __forceinline__ float flog(float x) {
  return __builtin_amdgcn_logf(x) * 0.69314718055995f;
}

// ---------------------------------------------------------------------------
// Setup: M = w_node2 @ w_ser2^T, bias folds, and PRNG keys
// keys = jax.random.split(key(1), 64): key t = threefry((0,1),(0,t)).
// ---------------------------------------------------------------------------
__global__ void setup_kernel(const float* __restrict__ w_node2,
                             const float* __restrict__ b_node2,
                             const float* __restrict__ w_ser2,
                             const float* __restrict__ b_ser2,
                             float* __restrict__ Mbuf, float* __restrict__ dvec,
                             unsigned* __restrict__ keys) {
  const int b = blockIdx.x, t = threadIdx.x;
  if (b < 128) {
    float acc = 0.0f;
    for (int e = 0; e < 128; ++e)
      acc = fmaf(w_node2[b * 128 + e], w_ser2[t * 128 + e], acc);
    Mbuf[b * 128 + t] = acc;
  } else if (b == 128) {
    float acc = 0.0f;
    for (int e = 0; e < 128; ++e)
      acc = fmaf(b_node2[e], w_ser2[t * 128 + e], acc);
    dvec[t] = acc;
  } else {
    if (t < 64) {
      unsigned o0, o1;
      threefry2x32(0u, 1u, 0u, (unsigned)t, o0, o1);
      keys[2 * t + 0] = o0;
      keys[2 * t + 1] = o1;
    }
  }
}

// ---------------------------------------------------------------------------
// K1: node_emb = silu(concat(tasks[:,:, :64], cons) @ w1 + b1) @ w2 + b2
// ---------------------------------------------------------------------------
__global__ __launch_bounds__(256, 2)
void init_mlp_kernel(const float* __restrict__ tasks,
                     const float* __restrict__ cons,
                     const float* __restrict__ w1, const float* __restrict__ b1,
                     const float* __restrict__ w2, const float* __restrict__ b2,
                     float* __restrict__ node_emb) {
  const int q = blockIdx.x, tid = threadIdx.x;
  const int lane = tid & 127, half = tid >> 7;
  __shared__ float xr[2][68];
  __shared__ float sgb[2][128];
  float w1r[68], w2r[128];
#pragma unroll
  for (int i = 0; i < 68; ++i) w1r[i] = w1[i * 128 + lane];
#pragma unroll
  for (int j = 0; j < 128; ++j) w2r[j] = w2[j * 128 + lane];
  const float bb1 = b1[lane], bb2 = b2[lane];
  for (int r = 0; r < 64; r += 2) {
    if (tid < 136) {
      const int rr = tid / 68, j = tid - rr * 68;
      xr[rr][j] = (j < 64) ? tasks[(q * 64 + r + rr) * TASKW + j]
                           : cons[q * 4 + (j - 64)];
    }
    __syncthreads();
    float g = 0.0f;
#pragma unroll
    for (int i = 0; i < 68; ++i) g = fmaf(xr[half][i], w1r[i], g);
    g += bb1;
    sgb[half][lane] = silu_f(g);
    __syncthreads();
    float o = 0.0f;
#pragma unroll
    for (int j = 0; j < 128; ++j) o = fmaf(sgb[half][j], w2r[j], o);
    node_emb[(q * 64 + r + half) * 128 + lane] = o + bb2;
    __syncthreads();
  }
}

// ---------------------------------------------------------------------------
// K2: fused MHA (QKV + scores + softmax + AV), no register arrays, all LDS.
// ---------------------------------------------------------------------------
__global__ __launch_bounds__(256, 2)
void mha_kernel(const float* __restrict__ node_emb,
                const float* __restrict__ wq, const float* __restrict__ bq,
                const float* __restrict__ wk, const float* __restrict__ bk,
                const float* __restrict__ wv, const float* __restrict__ bv,
                float* __restrict__ y_out) {
  const int q = blockIdx.x, tid = threadIdx.x;
  __shared__ float xs[64][130];
  __shared__ float qh[64][18];
  __shared__ float kh[64][18];
  __shared__ float vt[16][66];
  __shared__ float pool[3 * 16 * 130];  // wht[3][16][130] U at[64][66]
  float (*wht)[16][130] = (float (*)[16][130])pool;
  float (*at)[66] = (float (*)[66])pool;

  for (int idx = tid; idx < 64 * 128; idx += 256) {
    const int n = idx >> 7, e = idx & 127;
    xs[n][e] = node_emb[(q * 64 + n) * 128 + e];
  }
  __syncthreads();

  const int d16 = tid >> 4;  // 0..15
  const int ng = tid & 15;   // 0..15

  for (int hd = 0; hd < 8; ++hd) {
    for (int idx = tid; idx < 3 * 128 * 16; idx += 256) {
      const int m = idx >> 11, k = (idx >> 4) & 127, d = idx & 15;
      const float* W = (m == 0) ? wq : (m == 1) ? wk : wv;
      wht[m][d][k] = W[k * 128 + hd * 16 + d];
    }
    __syncthreads();

    {
      const float bqv = bq[hd * 16 + d16];
      const float bkv = bk[hd * 16 + d16];
      const float bvv = bv[hd * 16 + d16];
      const float2* wq2 = (const float2*)&wht[0][d16][0];
      const float2* wk2 = (const float2*)&wht[1][d16][0];
      const float2* wv2 = (const float2*)&wht[2][d16][0];
      const float2* xr0 = (const float2*)&xs[ng][0];
      const float2* xr1 = (const float2*)&xs[ng + 16][0];
      const float2* xr2 = (const float2*)&xs[ng + 32][0];
      const float2* xr3 = (const float2*)&xs[ng + 48][0];
      float aq0 = 0, aq1 = 0, aq2 = 0, aq3 = 0;
      float ak0 = 0, ak1 = 0, ak2 = 0, ak3 = 0;
      float av0 = 0, av1 = 0, av2 = 0, av3 = 0;
#pragma unroll 8
      for (int kk = 0; kk < 64; ++kk) {
        const float2 wqv = wq2[kk], wkv = wk2[kk], wvv = wv2[kk];
        const float2 x0 = xr0[kk], x1 = xr1[kk], x2 = xr2[kk], x3 = xr3[kk];
        aq0 = fmaf(x0.y, wqv.y, fmaf(x0.x, wqv.x, aq0));
        aq1 = fmaf(x1.y, wqv.y, fmaf(x1.x, wqv.x, aq1));
        aq2 = fmaf(x2.y, wqv.y, fmaf(x2.x, wqv.x, aq2));
        aq3 = fmaf(x3.y, wqv.y, fmaf(x3.x, wqv.x, aq3));
        ak0 = fmaf(x0.y, wkv.y, fmaf(x0.x, wkv.x, ak0));
        ak1 = fmaf(x1.y, wkv.y, fmaf(x1.x, wkv.x, ak1));
        ak2 = fmaf(x2.y, wkv.y, fmaf(x2.x, wkv.x, ak2));
        ak3 = fmaf(x3.y, wkv.y, fmaf(x3.x, wkv.x, ak3));
        av0 = fmaf(x0.y, wvv.y, fmaf(x0.x, wvv.x, av0));
        av1 = fmaf(x1.y, wvv.y, fmaf(x1.x, wvv.x, av1));
        av2 = fmaf(x2.y, wvv.y, fmaf(x2.x, wvv.x, av2));
        av3 = fmaf(x3.y, wvv.y, fmaf(x3.x, wvv.x, av3));
      }
      qh[ng][d16] = fmaxf(aq0 + bqv, 0.0f);
      qh[ng + 16][d16] = fmaxf(aq1 + bqv, 0.0f);
      qh[ng + 32][d16] = fmaxf(aq2 + bqv, 0.0f);
      qh[ng + 48][d16] = fmaxf(aq3 + bqv, 0.0f);
      kh[ng][d16] = fmaxf(ak0 + bkv, 0.0f);
      kh[ng + 16][d16] = fmaxf(ak1 + bkv, 0.0f);
      kh[ng + 32][d16] = fmaxf(ak2 + bkv, 0.0f);
      kh[ng + 48][d16] = fmaxf(ak3 + bkv, 0.0f);
      vt[d16][ng] = fmaxf(av0 + bvv, 0.0f);
      vt[d16][ng + 16] = fmaxf(av1 + bvv, 0.0f);
      vt[d16][ng + 32] = fmaxf(av2 + bvv, 0.0f);
      vt[d16][ng + 48] = fmaxf(av3 + bvv, 0.0f);
    }
    __syncthreads();

    {
      const int n = tid >> 2, mg = tid & 3;
      float2 qv[8];
      const float2* qrow = (const float2*)&qh[n][0];
#pragma unroll
      for (int kk = 0; kk < 8; ++kk) qv[kk] = qrow[kk];
#pragma unroll 4
      for (int jj = 0; jj < 16; ++jj) {
        const int m = mg + 4 * jj;
        const float2* krow = (const float2*)&kh[m][0];
        float acc = 0.0f;
#pragma unroll
        for (int kk = 0; kk < 8; ++kk) {
          const float2 kv = krow[kk];
          acc = fmaf(qv[kk].y, kv.y, fmaf(qv[kk].x, kv.x, acc));
        }
        at[n][m] = acc * 0.25f;
      }
    }
    __syncthreads();

    {
      const int r = tid >> 2, p = tid & 3;
      float mx = -1e30f;
#pragma unroll
      for (int t2 = 0; t2 < 16; ++t2) mx = fmaxf(mx, at[r][p * 16 + t2]);
      mx = fmaxf(mx, __shfl_xor(mx, 1, 64));
      mx = fmaxf(mx, __shfl_xor(mx, 2, 64));
      float s = 0.0f;
#pragma unroll
      for (int t2 = 0; t2 < 16; ++t2) {
        const float e = expf(at[r][p * 16 + t2] - mx);
        at[r][p * 16 + t2] = e;
        s += e;
      }
      s += __shfl_xor(s, 1, 64);
      s += __shfl_xor(s, 2, 64);
#pragma unroll
      for (int t2 = 0; t2 < 16; ++t2) at[r][p * 16 + t2] /= s;
    }
    __syncthreads();

    {
      const int dd = tid & 15, ngr = tid >> 4;
      const float2* vrow = (const float2*)&vt[dd][0];
      const float2* ar0 = (const float2*)&at[ngr][0];
      const float2* ar1 = (const float2*)&at[ngr + 16][0];
      const float2* ar2 = (const float2*)&at[ngr + 32][0];
      const float2* ar3 = (const float2*)&at[ngr + 48][0];
      float ac0 = 0, ac1 = 0, ac2 = 0, ac3 = 0;
#pragma unroll 8
      for (int kk = 0; kk < 32; ++kk) {
        const float2 vv = vrow[kk];
        const float2 a0 = ar0[kk], a1 = ar1[kk], a2 = ar2[kk], a3 = ar3[kk];
        ac0 = fmaf(a0.y, vv.y, fmaf(a0.x, vv.x, ac0));
        ac1 = fmaf(a1.y, vv.y, fmaf(a1.x, vv.x, ac1));
        ac2 = fmaf(a2.y, vv.y, fmaf(a2.x, vv.x, ac2));
        ac3 = fmaf(a3.y, vv.y, fmaf(a3.x, vv.x, ac3));
      }
      y_out[(q * 64 + ngr) * 128 + hd * 16 + dd] = ac0;
      y_out[(q * 64 + ngr + 16) * 128 + hd * 16 + dd] = ac1;
      y_out[(q * 64 + ngr + 32) * 128 + hd * 16 + dd] = ac2;
      y_out[(q * 64 + ngr + 48) * 128 + hd * 16 + dd] = ac3;
    }
    __syncthreads();
  }
}

// ---------------------------------------------------------------------------
// K3: nodes_emb = relu(y @ wo + bo) + node_emb   (LDS-tiled)
// ---------------------------------------------------------------------------
__global__ __launch_bounds__(256, 4)
void outproj_kernel(const float* __restrict__ node_emb,
                    const float* __restrict__ wo, const float* __restrict__ bo,
                    float* __restrict__ nodes_emb) {
  const int q = blockIdx.x, tid = threadIdx.x;
  __shared__ float ys[64][130];
  __shared__ float wot[32][130];
  for (int idx = tid; idx < 64 * 128; idx += 256) {
    const int n = idx >> 7, e = idx & 127;
    ys[n][e] = nodes_emb[(q * 64 + n) * 128 + e];
  }
  const int cg = tid & 15, ngr = tid >> 4;
  for (int c0 = 0; c0 < 128; c0 += 32) {
    __syncthreads();
    for (int idx = tid; idx < 32 * 128; idx += 256) {
      const int k = idx >> 5, c = idx & 31;
      wot[c][k] = wo[k * 128 + c0 + c];
    }
    __syncthreads();
    const int c = c0 + 2 * cg;
    const float2* w0 = (const float2*)&wot[2 * cg][0];
    const float2* w1 = (const float2*)&wot[2 * cg + 1][0];
    const float2* yr0 = (const float2*)&ys[ngr][0];
    const float2* yr1 = (const float2*)&ys[ngr + 16][0];
    const float2* yr2 = (const float2*)&ys[ngr + 32][0];
    const float2* yr3 = (const float2*)&ys[ngr + 48][0];
    float a00 = 0, a01 = 0, a10 = 0, a11 = 0;
    float a20 = 0, a21 = 0, a30 = 0, a31 = 0;
#pragma unroll 8
    for (int kk = 0; kk < 64; ++kk) {
      const float2 wv0 = w0[kk], wv1 = w1[kk];
      const float2 x0 = yr0[kk], x1 = yr1[kk], x2 = yr2[kk], x3 = yr3[kk];
      a00 = fmaf(x0.y, wv0.y, fmaf(x0.x, wv0.x, a00));
      a01 = fmaf(x0.y, wv1.y, fmaf(x0.x, wv1.x, a01));
      a10 = fmaf(x1.y, wv0.y, fmaf(x1.x, wv0.x, a10));
      a11 = fmaf(x1.y, wv1.y, fmaf(x1.x, wv1.x, a11));
      a20 = fmaf(x2.y, wv0.y, fmaf(x2.x, wv0.x, a20));
      a21 = fmaf(x2.y, wv1.y, fmaf(x2.x, wv1.x, a21));
      a30 = fmaf(x3.y, wv0.y, fmaf(x3.x, wv0.x, a30));
      a31 = fmaf(x3.y, wv1.y, fmaf(x3.x, wv1.x, a31));
    }
    const float b0v = bo[c], b1v = bo[c + 1];
#define OUTP_EMIT(J, A0, A1)                                                  \
    {                                                                         \
      const int n = ngr + 16 * J;                                             \
      const float2 res = *(const float2*)&node_emb[(q * 64 + n) * 128 + c];   \
      float2 o;                                                               \
      o.x = fmaxf(A0 + b0v, 0.0f) + res.x;                                    \
      o.y = fmaxf(A1 + b1v, 0.0f) + res.y;                                    \
      *(float2*)&nodes_emb[(q * 64 + n) * 128 + c] = o;                       \
    }
    OUTP_EMIT(0, a00, a01)
    OUTP_EMIT(1, a10, a11)
    OUTP_EMIT(2, a20, a21)
    OUTP_EMIT(3, a30, a31)
#undef OUTP_EMIT
  }
}

// ---------------------------------------------------------------------------
// K4: 64-step scan, one workgroup per q. Fast-math transcendentals, packed
// LDS for the logits loop, c-term dropped (softmax/argmax shift-invariant),
// 8 barriers/step.
// ---------------------------------------------------------------------------
__global__ __launch_bounds__(256, 2)
void scan_kernel(const float* __restrict__ tasks, const int* __restrict__ masks,
                 const int* __restrict__ topologicals,
                 const float* __restrict__ w_node1,
                 const float* __restrict__ b_node1,
                 const float* __restrict__ w_ser1,
                 const float* __restrict__ b_ser1,
                 const float* __restrict__ nodes_emb,
                 const float* __restrict__ Mbuf, const float* __restrict__ dvec,
                 const unsigned* __restrict__ keys, float* __restrict__ out) {
  const int q = blockIdx.x, tid = threadIdx.x;
  const int lane = tid & 127, half = tid >> 7;

  __shared__ float task_s[TASKW];
  __shared__ float node_e[128];
  __shared__ float sg[128];
  __shared__ float4 wst4[128];   // w_ser1 transposed: (w0,w1,w2,w3) per h
  __shared__ float2 hp[128];     // per-step pack: (b_ser1[h], uu[h])
  __shared__ float logit_s[128];
  __shared__ float gl[128];
  __shared__ float red[256];
  __shared__ float qos_s[64 * 4];
  __shared__ float ridx_s[64], rprob_s[64];
  __shared__ float qw[4][128];   // w_node1 rows 128..131 (qos features)
  __shared__ float dvs[128];
  __shared__ float scal[8];      // 0:rt 1:ava 2:tp 3:rel 5:mx 6:sumexp
  __shared__ int mask_s[128];
  __shared__ int sidx_s;
  __shared__ unsigned keys_s[128];

  // Register-resident weight columns (64+64 = 128 VGPRs)
  float w1r[64];
#pragma unroll
  for (int j = 0; j < 64; ++j) w1r[j] = w_node1[(half * 64 + j) * 128 + lane];
  float Mr[64];
#pragma unroll
  for (int j = 0; j < 64; ++j) Mr[j] = Mbuf[(half * 64 + j) * 128 + lane];

  if (tid < 128) {
    wst4[tid] = make_float4(w_ser1[tid], w_ser1[128 + tid], w_ser1[256 + tid],
                            w_ser1[384 + tid]);
    dvs[tid] = dvec[tid];
    keys_s[tid] = keys[tid];
  }
  for (int i = tid; i < 512; i += 256)
    qw[i >> 7][i & 127] = w_node1[(128 + (i >> 7)) * 128 + (i & 127)];
  if (tid < 64) {
    qos_s[tid * 4 + 0] = 3.0f;
    qos_s[tid * 4 + 1] = 1.0f;
    qos_s[tid * 4 + 2] = 0.0f;
    qos_s[tid * 4 + 3] = 1.0f;
    ridx_s[tid] = 0.0f;
    rprob_s[tid] = 0.0f;
  }
  if (tid == 0) { scal[1] = 1.0f; scal[2] = 3.0f; scal[3] = 1.0f; }
  const float b1l = b_node1[lane];
  const float bsl = b_ser1[lane];
  __syncthreads();

  for (int t = 0; t < 64; ++t) {
    const int topo = topologicals[q * 64 + (63 - t)];  // topo_seq reversal
    {
      const float4* src = (const float4*)(tasks + (size_t)(q * 64 + topo) * TASKW);
      if (tid < 144) ((float4*)task_s)[tid] = src[tid];
    }
    if (tid < 128) {
      node_e[tid] = nodes_emb[(q * 64 + topo) * 128 + tid];
      mask_s[tid] = masks[(q * 64 + topo) * 128 + tid];
    }
    __syncthreads();

    // wave0: rt = max_n(workflow[n]*qos[n,0]); all: g node-part partial
    if (tid < 64) {
      float p = task_s[tid] * qos_s[tid * 4];
#pragma unroll
      for (int o = 32; o > 0; o >>= 1) p = fmaxf(p, __shfl_xor(p, o, 64));
      if (tid == 0) scal[0] = p;
    }
    {
      float acc = 0.0f;
      const float2* ne2 = (const float2*)node_e + half * 32;
#pragma unroll
      for (int j = 0; j < 32; ++j) {
        const float2 x = ne2[j];
        acc = fmaf(x.x, w1r[2 * j], acc);
        acc = fmaf(x.y, w1r[2 * j + 1], acc);
      }
      red[tid] = acc;
    }
    __syncthreads();

    const float rt = scal[0], ava = scal[1], tp = scal[2], rel = scal[3];
    if (tid < 128) {
      float g = red[tid] + red[tid + 128] + b1l;
      g = fmaf(rt, qw[0][tid], g);
      g = fmaf(ava, qw[1][tid], g);
      g = fmaf(tp, qw[2][tid], g);
      g = fmaf(rel, qw[3][tid], g);
      sg[tid] = fsilu(g);
    }
    __syncthreads();

    // u = silu(g) @ M + dvec (partials)
    {
      float acc = 0.0f;
      const float2* sg2 = (const float2*)sg + half * 32;
#pragma unroll
      for (int j = 0; j < 32; ++j) {
        const float2 x = sg2[j];
        acc = fmaf(x.x, Mr[2 * j], acc);
        acc = fmaf(x.y, Mr[2 * j + 1], acc);
      }
      red[tid] = acc;
    }
    __syncthreads();
    if (tid < 128) {
      const float uu = red[tid] + red[tid + 128] + dvs[tid];
      hp[tid] = make_float2(bsl, uu);
    }
    __syncthreads();

    // logits[s] partial over h-half: 2 LDS + 10 VALU per h
    {
      const float4 sv = *(const float4*)&task_s[64 + 4 * lane];
      float acc = 0.0f;
      const int hb = half * 64;
#pragma unroll 16
      for (int j = 0; j < 64; ++j) {
        const int h = hb + j;
        const float4 w = wst4[h];
        const float2 hb2 = hp[h];
        float h1 = fmaf(sv.x, w.x, hb2.x);
        h1 = fmaf(sv.y, w.y, h1);
        h1 = fmaf(sv.z, w.z, h1);
        h1 = fmaf(sv.w, w.w, h1);
        const float e = __builtin_amdgcn_exp2f(h1 * -1.44269504088896f);
        const float r = __builtin_amdgcn_rcpf(1.0f + e);
        acc = fmaf(h1 * r, hb2.y, acc);
      }
      red[tid] = acc;
    }
    __syncthreads();

    if (tid < 128) {
      float l = red[tid] + red[tid + 128];
      if (mask_s[tid] == 0) l = NEGV;
      logit_s[tid] = l;
      unsigned o0, o1;
      threefry2x32(keys_s[2 * t], keys_s[2 * t + 1], 0u,
                   (unsigned)(q * 128 + tid), o0, o1);
      const unsigned bits = o0 ^ o1;
      const float f = __uint_as_float((bits >> 9) | 0x3f800000u) - 1.0f;
      const float u = (f > 0.0f) ? f : 1.17549435e-38f;
      const float gmb = -flog(-flog(u));
      gl[tid] = l + gmb;
    }
    __syncthreads();

    // wave0: argmax(gl); wave1: mx + sumexp (no barrier between)
    if (tid < 64) {
      float z = gl[tid];
      int zi = tid;
      const float z2 = gl[tid + 64];
      if (z2 > z) { z = z2; zi = tid + 64; }
#pragma unroll
      for (int o = 32; o > 0; o >>= 1) {
        const float zo = __shfl_xor(z, o, 64);
        const int io = __shfl_xor(zi, o, 64);
        if (zo > z || (zo == z && io < zi)) { z = zo; zi = io; }
      }
      if (tid == 0) sidx_s = zi;
    } else if (tid < 128) {
      const int l2 = tid - 64;
      const float la = logit_s[l2], lb = logit_s[l2 + 64];
      float mx = fmaxf(la, lb);
#pragma unroll
      for (int o = 32; o > 0; o >>= 1) mx = fmaxf(mx, __shfl_xor(mx, o, 64));
      float e = fexp(la - mx) + fexp(lb - mx);
#pragma unroll
      for (int o = 32; o > 0; o >>= 1) e += __shfl_xor(e, o, 64);
      if (l2 == 0) { scal[5] = mx; scal[6] = e; }
    }
    __syncthreads();

    if (tid == 0) {
      const int si = sidx_s;
      const float prob = fexp(logit_s[si] - scal[5]) / scal[6];
      const float4 s4 = *(const float4*)&task_s[64 + 4 * si];
      const float nava = s4.y * ava;
      const float ntp = fminf(s4.z, tp);
      const float nrel = s4.w * rel;
      qos_s[topo * 4 + 0] = s4.x + rt;
      qos_s[topo * 4 + 1] = nava;
      qos_s[topo * 4 + 2] = ntp;
      qos_s[topo * 4 + 3] = nrel;
      scal[1] = nava;
      scal[2] = ntp;
      scal[3] = nrel;
      ridx_s[topo] += (float)si;
      rprob_s[topo] += prob;
    }
    __syncthreads();
  }
  if (tid < 64) {
    out[q * 64 + tid] = ridx_s[tid];
    out[Qn * Nn + q * 64 + tid] = rprob_s[tid];
  }
}

// ---------------------------------------------------------------------------
extern "C" void kernel_launch(void* const* d_in, const int* in_sizes, int n_in,
                              void* d_out, int out_size, void* d_ws,
                              size_t ws_size, hipStream_t stream) {
  const float* tasks = (const float*)d_in[0];
  const float* constraints = (const float*)d_in[1];
  const int* masks = (const int*)d_in[2];
  const int* topologicals = (const int*)d_in[3];
  const float* w_init1 = (const float*)d_in[4];
  const float* b_init1 = (const float*)d_in[5];
  const float* w_init2 = (const float*)d_in[6];
  const float* b_init2 = (const float*)d_in[7];
  const float* wq = (const float*)d_in[8];
  const float* bq = (const float*)d_in[9];
  const float* wk = (const float*)d_in[10];
  const float* bk = (const float*)d_in[11];
  const float* wv = (const float*)d_in[12];
  const float* bv = (const float*)d_in[13];
  const float* wo = (const float*)d_in[14];
  const float* bo = (const float*)d_in[15];
  const float* w_node1 = (const float*)d_in[16];
  const float* b_node1 = (const float*)d_in[17];
  const float* w_node2 = (const float*)d_in[18];
  const float* b_node2 = (const float*)d_in[19];
  const float* w_ser1 = (const float*)d_in[20];
  const float* b_ser1 = (const float*)d_in[21];
  const float* w_ser2 = (const float*)d_in[22];
  const float* b_ser2 = (const float*)d_in[23];

  float* ws = (float*)d_ws;
  float* node_emb = ws;                                // Q*N*E
  float* nodes_emb = node_emb + (size_t)Qn * Nn * En;  // Q*N*E (y, then final)
  float* Mbuf = nodes_emb + (size_t)Qn * Nn * En;      // 128*128
  float* dvec = Mbuf + 128 * 128;
  unsigned* keys = (unsigned*)(dvec + 128);            // 128 u32

  setup_kernel<<<130, 128, 0, stream>>>(w_node2, b_node2, w_ser2, b_ser2, Mbuf,
                                        dvec, keys);
  init_mlp_kernel<<<Qn, 256, 0, stream>>>(tasks, constraints, w_init1, b_init1,
                                          w_init2, b_init2, node_emb);
  mha_kernel<<<Qn, 256, 0, stream>>>(node_emb, wq, bq, wk, bk, wv, bv,
                                     nodes_emb);
  outproj_kernel<<<Qn, 256, 0, stream>>>(node_emb, wo, bo, nodes_emb);
  scan_kernel<<<Qn, 256, 0, stream>>>(tasks, masks, topologicals, w_node1,
                                      b_node1, w_ser1, b_ser1, nodes_emb, Mbuf,
                                      dvec, keys, (float*)d_out);
}

// Round 4
// 2310.748 us; speedup vs baseline: 7.5519x; 1.2670x over previous
//
#include <hip/hip_runtime.h>
#include <math.h>

// Problem constants
#define Qn 2048
#define Nn 64
#define Sn 128
#define An 4
#define En 128
#define TASKW 576  // N + 4*S
#define NEGV -1000000000.0f

// ---------------------------------------------------------------------------
// Threefry-2x32 (20 rounds), matches JAX's threefry2x32_p exactly.
// ---------------------------------------------------------------------------
__device__ __forceinline__ void threefry2x32(unsigned k0, unsigned k1,
                                             unsigned x0, unsigned x1,
                                             unsigned& o0, unsigned& o1) {
  unsigned ks2 = k0 ^ k1 ^ 0x1BD11BDAu;
  x0 += k0; x1 += k1;
#define TFR(r) { x0 += x1; x1 = (x1 << (r)) | (x1 >> (32 - (r))); x1 ^= x0; }
  TFR(13) TFR(15) TFR(26) TFR(6)
  x0 += k1;  x1 += ks2 + 1u;
  TFR(17) TFR(29) TFR(16) TFR(24)
  x0 += ks2; x1 += k0 + 2u;
  TFR(13) TFR(15) TFR(26) TFR(6)
  x0 += k0;  x1 += k1 + 3u;
  TFR(17) TFR(29) TFR(16) TFR(24)
  x0 += k1;  x1 += ks2 + 4u;
  TFR(13) TFR(15) TFR(26) TFR(6)
  x0 += ks2; x1 += k0 + 5u;
#undef TFR
  o0 = x0; o1 = x1;
}

__device__ __forceinline__ float silu_f(float x) {
  return x / (1.0f + expf(-x));
}

// Fast-math helpers (v_exp_f32 / v_log_f32 / v_rcp_f32; ~1 ulp)
__device__ __forceinline__ float fexp(float x) {
  return __builtin_amdgcn_exp2f(x * 1.44269504088896f);
}
__device__ __forceinline__ float fsilu(float x) {
  const float e = __builtin_amdgcn_exp2f(x * -1.44269504088896f);
  return x * __builtin_amdgcn_rcpf(1.0f + e);
}
__device__ __forceinline__ float flog(float x) {
  return __builtin_amdgcn_logf(x) * 0.69314718055995f;
}

// ---------------------------------------------------------------------------
// Setup: M = w_node2 @ w_ser2^T, dvec fold, PRNG keys
// ---------------------------------------------------------------------------
__global__ void setup_kernel(const float* __restrict__ w_node2,
                             const float* __restrict__ b_node2,
                             const float* __restrict__ w_ser2,
                             const float* __restrict__ b_ser2,
                             float* __restrict__ Mbuf, float* __restrict__ dvec,
                             unsigned* __restrict__ keys) {
  const int b = blockIdx.x, t = threadIdx.x;
  if (b < 128) {
    float acc = 0.0f;
    for (int e = 0; e < 128; ++e)
      acc = fmaf(w_node2[b * 128 + e], w_ser2[t * 128 + e], acc);
    Mbuf[b * 128 + t] = acc;
  } else if (b == 128) {
    float acc = 0.0f;
    for (int e = 0; e < 128; ++e)
      acc = fmaf(b_node2[e], w_ser2[t * 128 + e], acc);
    dvec[t] = acc;
  } else {
    if (t < 64) {
      unsigned o0, o1;
      threefry2x32(0u, 1u, 0u, (unsigned)t, o0, o1);
      keys[2 * t + 0] = o0;
      keys[2 * t + 1] = o1;
    }
  }
}

// ---------------------------------------------------------------------------
// K1: node_emb = silu(concat(tasks[:,:, :64], cons) @ w1 + b1) @ w2 + b2
// ---------------------------------------------------------------------------
__global__ __launch_bounds__(256, 2)
void init_mlp_kernel(const float* __restrict__ tasks,
                     const float* __restrict__ cons,
                     const float* __restrict__ w1, const float* __restrict__ b1,
                     const float* __restrict__ w2, const float* __restrict__ b2,
                     float* __restrict__ node_emb) {
  const int q = blockIdx.x, tid = threadIdx.x;
  const int lane = tid & 127, half = tid >> 7;
  __shared__ float xr[2][68];
  __shared__ float sgb[2][128];
  float w1r[68], w2r[128];
#pragma unroll
  for (int i = 0; i < 68; ++i) w1r[i] = w1[i * 128 + lane];
#pragma unroll
  for (int j = 0; j < 128; ++j) w2r[j] = w2[j * 128 + lane];
  const float bb1 = b1[lane], bb2 = b2[lane];
  for (int r = 0; r < 64; r += 2) {
    if (tid < 136) {
      const int rr = tid / 68, j = tid - rr * 68;
      xr[rr][j] = (j < 64) ? tasks[(q * 64 + r + rr) * TASKW + j]
                           : cons[q * 4 + (j - 64)];
    }
    __syncthreads();
    float g = 0.0f;
#pragma unroll
    for (int i = 0; i < 68; ++i) g = fmaf(xr[half][i], w1r[i], g);
    g += bb1;
    sgb[half][lane] = silu_f(g);
    __syncthreads();
    float o = 0.0f;
#pragma unroll
    for (int j = 0; j < 128; ++j) o = fmaf(sgb[half][j], w2r[j], o);
    node_emb[(q * 64 + r + half) * 128 + lane] = o + bb2;
    __syncthreads();
  }
}

// ---------------------------------------------------------------------------
// K2: fused MHA (QKV + scores + softmax + AV)
// ---------------------------------------------------------------------------
__global__ __launch_bounds__(256, 2)
void mha_kernel(const float* __restrict__ node_emb,
                const float* __restrict__ wq, const float* __restrict__ bq,
                const float* __restrict__ wk, const float* __restrict__ bk,
                const float* __restrict__ wv, const float* __restrict__ bv,
                float* __restrict__ y_out) {
  const int q = blockIdx.x, tid = threadIdx.x;
  __shared__ float xs[64][130];
  __shared__ float qh[64][18];
  __shared__ float kh[64][18];
  __shared__ float vt[16][66];
  __shared__ float pool[3 * 16 * 130];  // wht[3][16][130] U at[64][66]
  float (*wht)[16][130] = (float (*)[16][130])pool;
  float (*at)[66] = (float (*)[66])pool;

  for (int idx = tid; idx < 64 * 128; idx += 256) {
    const int n = idx >> 7, e = idx & 127;
    xs[n][e] = node_emb[(q * 64 + n) * 128 + e];
  }
  __syncthreads();

  const int d16 = tid >> 4;  // 0..15
  const int ng = tid & 15;   // 0..15

  for (int hd = 0; hd < 8; ++hd) {
    for (int idx = tid; idx < 3 * 128 * 16; idx += 256) {
      const int m = idx >> 11, k = (idx >> 4) & 127, d = idx & 15;
      const float* W = (m == 0) ? wq : (m == 1) ? wk : wv;
      wht[m][d][k] = W[k * 128 + hd * 16 + d];
    }
    __syncthreads();

    {
      const float bqv = bq[hd * 16 + d16];
      const float bkv = bk[hd * 16 + d16];
      const float bvv = bv[hd * 16 + d16];
      const float2* wq2 = (const float2*)&wht[0][d16][0];
      const float2* wk2 = (const float2*)&wht[1][d16][0];
      const float2* wv2 = (const float2*)&wht[2][d16][0];
      const float2* xr0 = (const float2*)&xs[ng][0];
      const float2* xr1 = (const float2*)&xs[ng + 16][0];
      const float2* xr2 = (const float2*)&xs[ng + 32][0];
      const float2* xr3 = (const float2*)&xs[ng + 48][0];
      float aq0 = 0, aq1 = 0, aq2 = 0, aq3 = 0;
      float ak0 = 0, ak1 = 0, ak2 = 0, ak3 = 0;
      float av0 = 0, av1 = 0, av2 = 0, av3 = 0;
#pragma unroll 8
      for (int kk = 0; kk < 64; ++kk) {
        const float2 wqv = wq2[kk], wkv = wk2[kk], wvv = wv2[kk];
        const float2 x0 = xr0[kk], x1 = xr1[kk], x2 = xr2[kk], x3 = xr3[kk];
        aq0 = fmaf(x0.y, wqv.y, fmaf(x0.x, wqv.x, aq0));
        aq1 = fmaf(x1.y, wqv.y, fmaf(x1.x, wqv.x, aq1));
        aq2 = fmaf(x2.y, wqv.y, fmaf(x2.x, wqv.x, aq2));
        aq3 = fmaf(x3.y, wqv.y, fmaf(x3.x, wqv.x, aq3));
        ak0 = fmaf(x0.y, wkv.y, fmaf(x0.x, wkv.x, ak0));
        ak1 = fmaf(x1.y, wkv.y, fmaf(x1.x, wkv.x, ak1));
        ak2 = fmaf(x2.y, wkv.y, fmaf(x2.x, wkv.x, ak2));
        ak3 = fmaf(x3.y, wkv.y, fmaf(x3.x, wkv.x, ak3));
        av0 = fmaf(x0.y, wvv.y, fmaf(x0.x, wvv.x, av0));
        av1 = fmaf(x1.y, wvv.y, fmaf(x1.x, wvv.x, av1));
        av2 = fmaf(x2.y, wvv.y, fmaf(x2.x, wvv.x, av2));
        av3 = fmaf(x3.y, wvv.y, fmaf(x3.x, wvv.x, av3));
      }
      qh[ng][d16] = fmaxf(aq0 + bqv, 0.0f);
      qh[ng + 16][d16] = fmaxf(aq1 + bqv, 0.0f);
      qh[ng + 32][d16] = fmaxf(aq2 + bqv, 0.0f);
      qh[ng + 48][d16] = fmaxf(aq3 + bqv, 0.0f);
      kh[ng][d16] = fmaxf(ak0 + bkv, 0.0f);
      kh[ng + 16][d16] = fmaxf(ak1 + bkv, 0.0f);
      kh[ng + 32][d16] = fmaxf(ak2 + bkv, 0.0f);
      kh[ng + 48][d16] = fmaxf(ak3 + bkv, 0.0f);
      vt[d16][ng] = fmaxf(av0 + bvv, 0.0f);
      vt[d16][ng + 16] = fmaxf(av1 + bvv, 0.0f);
      vt[d16][ng + 32] = fmaxf(av2 + bvv, 0.0f);
      vt[d16][ng + 48] = fmaxf(av3 + bvv, 0.0f);
    }
    __syncthreads();

    {
      const int n = tid >> 2, mg = tid & 3;
      float2 qv[8];
      const float2* qrow = (const float2*)&qh[n][0];
#pragma unroll
      for (int kk = 0; kk < 8; ++kk) qv[kk] = qrow[kk];
#pragma unroll 4
      for (int jj = 0; jj < 16; ++jj) {
        const int m = mg + 4 * jj;
        const float2* krow = (const float2*)&kh[m][0];
        float acc = 0.0f;
#pragma unroll
        for (int kk = 0; kk < 8; ++kk) {
          const float2 kv = krow[kk];
          acc = fmaf(qv[kk].y, kv.y, fmaf(qv[kk].x, kv.x, acc));
        }
        at[n][m] = acc * 0.25f;
      }
    }
    __syncthreads();

    {
      const int r = tid >> 2, p = tid & 3;
      float mx = -1e30f;
#pragma unroll
      for (int t2 = 0; t2 < 16; ++t2) mx = fmaxf(mx, at[r][p * 16 + t2]);
      mx = fmaxf(mx, __shfl_xor(mx, 1, 64));
      mx = fmaxf(mx, __shfl_xor(mx, 2, 64));
      float s = 0.0f;
#pragma unroll
      for (int t2 = 0; t2 < 16; ++t2) {
        const float e = fexp(at[r][p * 16 + t2] - mx);
        at[r][p * 16 + t2] = e;
        s += e;
      }
      s += __shfl_xor(s, 1, 64);
      s += __shfl_xor(s, 2, 64);
      const float rs = __builtin_amdgcn_rcpf(s);
#pragma unroll
      for (int t2 = 0; t2 < 16; ++t2) at[r][p * 16 + t2] *= rs;
    }
    __syncthreads();

    {
      const int dd = tid & 15, ngr = tid >> 4;
      const float2* vrow = (const float2*)&vt[dd][0];
      const float2* ar0 = (const float2*)&at[ngr][0];
      const float2* ar1 = (const float2*)&at[ngr + 16][0];
      const float2* ar2 = (const float2*)&at[ngr + 32][0];
      const float2* ar3 = (const float2*)&at[ngr + 48][0];
      float ac0 = 0, ac1 = 0, ac2 = 0, ac3 = 0;
#pragma unroll 8
      for (int kk = 0; kk < 32; ++kk) {
        const float2 vv = vrow[kk];
        const float2 a0 = ar0[kk], a1 = ar1[kk], a2 = ar2[kk], a3 = ar3[kk];
        ac0 = fmaf(a0.y, vv.y, fmaf(a0.x, vv.x, ac0));
        ac1 = fmaf(a1.y, vv.y, fmaf(a1.x, vv.x, ac1));
        ac2 = fmaf(a2.y, vv.y, fmaf(a2.x, vv.x, ac2));
        ac3 = fmaf(a3.y, vv.y, fmaf(a3.x, vv.x, ac3));
      }
      y_out[(q * 64 + ngr) * 128 + hd * 16 + dd] = ac0;
      y_out[(q * 64 + ngr + 16) * 128 + hd * 16 + dd] = ac1;
      y_out[(q * 64 + ngr + 32) * 128 + hd * 16 + dd] = ac2;
      y_out[(q * 64 + ngr + 48) * 128 + hd * 16 + dd] = ac3;
    }
    __syncthreads();
  }
}

// ---------------------------------------------------------------------------
// K3: nodes_emb = relu(y @ wo + bo) + node_emb   (LDS-tiled)
// ---------------------------------------------------------------------------
__global__ __launch_bounds__(256, 4)
void outproj_kernel(const float* __restrict__ node_emb,
                    const float* __restrict__ wo, const float* __restrict__ bo,
                    float* __restrict__ nodes_emb) {
  const int q = blockIdx.x, tid = threadIdx.x;
  __shared__ float ys[64][130];
  __shared__ float wot[32][130];
  for (int idx = tid; idx < 64 * 128; idx += 256) {
    const int n = idx >> 7, e = idx & 127;
    ys[n][e] = nodes_emb[(q * 64 + n) * 128 + e];
  }
  const int cg = tid & 15, ngr = tid >> 4;
  for (int c0 = 0; c0 < 128; c0 += 32) {
    __syncthreads();
    for (int idx = tid; idx < 32 * 128; idx += 256) {
      const int k = idx >> 5, c = idx & 31;
      wot[c][k] = wo[k * 128 + c0 + c];
    }
    __syncthreads();
    const int c = c0 + 2 * cg;
    const float2* w0 = (const float2*)&wot[2 * cg][0];
    const float2* w1 = (const float2*)&wot[2 * cg + 1][0];
    const float2* yr0 = (const float2*)&ys[ngr][0];
    const float2* yr1 = (const float2*)&ys[ngr + 16][0];
    const float2* yr2 = (const float2*)&ys[ngr + 32][0];
    const float2* yr3 = (const float2*)&ys[ngr + 48][0];
    float a00 = 0, a01 = 0, a10 = 0, a11 = 0;
    float a20 = 0, a21 = 0, a30 = 0, a31 = 0;
#pragma unroll 8
    for (int kk = 0; kk < 64; ++kk) {
      const float2 wv0 = w0[kk], wv1 = w1[kk];
      const float2 x0 = yr0[kk], x1 = yr1[kk], x2 = yr2[kk], x3 = yr3[kk];
      a00 = fmaf(x0.y, wv0.y, fmaf(x0.x, wv0.x, a00));
      a01 = fmaf(x0.y, wv1.y, fmaf(x0.x, wv1.x, a01));
      a10 = fmaf(x1.y, wv0.y, fmaf(x1.x, wv0.x, a10));
      a11 = fmaf(x1.y, wv1.y, fmaf(x1.x, wv1.x, a11));
      a20 = fmaf(x2.y, wv0.y, fmaf(x2.x, wv0.x, a20));
      a21 = fmaf(x2.y, wv1.y, fmaf(x2.x, wv1.x, a21));
      a30 = fmaf(x3.y, wv0.y, fmaf(x3.x, wv0.x, a30));
      a31 = fmaf(x3.y, wv1.y, fmaf(x3.x, wv1.x, a31));
    }
    const float b0v = bo[c], b1v = bo[c + 1];
#define OUTP_EMIT(J, A0, A1)                                                  \
    {                                                                         \
      const int n = ngr + 16 * J;                                             \
      const float2 res = *(const float2*)&node_emb[(q * 64 + n) * 128 + c];   \
      float2 o;                                                               \
      o.x = fmaxf(A0 + b0v, 0.0f) + res.x;                                    \
      o.y = fmaxf(A1 + b1v, 0.0f) + res.y;                                    \
      *(float2*)&nodes_emb[(q * 64 + n) * 128 + c] = o;                       \
    }
    OUTP_EMIT(0, a00, a01)
    OUTP_EMIT(1, a10, a11)
    OUTP_EMIT(2, a20, a21)
    OUTP_EMIT(3, a30, a31)
#undef OUTP_EMIT
  }
}

// ---------------------------------------------------------------------------
// K3b: gbase[q,n,e] = sum_j nodes_emb[q,n,j]*w_node1[j,e] + b_node1[e]
// (state-independent node part of the scan's g matvec, hoisted out)
// ---------------------------------------------------------------------------
__global__ __launch_bounds__(256, 4)
void gbase_kernel(const float* __restrict__ nodes_emb,
                  const float* __restrict__ w_node1,
                  const float* __restrict__ b_node1,
                  float* __restrict__ gbase) {
  const int q = blockIdx.x, tid = threadIdx.x;
  __shared__ float ys[64][130];
  __shared__ float wot[32][130];
  for (int idx = tid; idx < 64 * 128; idx += 256) {
    const int n = idx >> 7, e = idx & 127;
    ys[n][e] = nodes_emb[(q * 64 + n) * 128 + e];
  }
  const int cg = tid & 15, ngr = tid >> 4;
  for (int c0 = 0; c0 < 128; c0 += 32) {
    __syncthreads();
    for (int idx = tid; idx < 32 * 128; idx += 256) {
      const int k = idx >> 5, c = idx & 31;
      wot[c][k] = w_node1[k * 128 + c0 + c];
    }
    __syncthreads();
    const int c = c0 + 2 * cg;
    const float2* w0 = (const float2*)&wot[2 * cg][0];
    const float2* w1 = (const float2*)&wot[2 * cg + 1][0];
    const float2* yr0 = (const float2*)&ys[ngr][0];
    const float2* yr1 = (const float2*)&ys[ngr + 16][0];
    const float2* yr2 = (const float2*)&ys[ngr + 32][0];
    const float2* yr3 = (const float2*)&ys[ngr + 48][0];
    float a00 = 0, a01 = 0, a10 = 0, a11 = 0;
    float a20 = 0, a21 = 0, a30 = 0, a31 = 0;
#pragma unroll 8
    for (int kk = 0; kk < 64; ++kk) {
      const float2 wv0 = w0[kk], wv1 = w1[kk];
      const float2 x0 = yr0[kk], x1 = yr1[kk], x2 = yr2[kk], x3 = yr3[kk];
      a00 = fmaf(x0.y, wv0.y, fmaf(x0.x, wv0.x, a00));
      a01 = fmaf(x0.y, wv1.y, fmaf(x0.x, wv1.x, a01));
      a10 = fmaf(x1.y, wv0.y, fmaf(x1.x, wv0.x, a10));
      a11 = fmaf(x1.y, wv1.y, fmaf(x1.x, wv1.x, a11));
      a20 = fmaf(x2.y, wv0.y, fmaf(x2.x, wv0.x, a20));
      a21 = fmaf(x2.y, wv1.y, fmaf(x2.x, wv1.x, a21));
      a30 = fmaf(x3.y, wv0.y, fmaf(x3.x, wv0.x, a30));
      a31 = fmaf(x3.y, wv1.y, fmaf(x3.x, wv1.x, a31));
    }
    const float b0v = b_node1[c], b1v = b_node1[c + 1];
#define GB_EMIT(J, A0, A1)                                                    \
    {                                                                         \
      const int n = ngr + 16 * J;                                             \
      float2 o;                                                               \
      o.x = A0 + b0v;                                                         \
      o.y = A1 + b1v;                                                         \
      *(float2*)&gbase[(q * 64 + n) * 128 + c] = o;                           \
    }
    GB_EMIT(0, a00, a01)
    GB_EMIT(1, a10, a11)
    GB_EMIT(2, a20, a21)
    GB_EMIT(3, a30, a31)
#undef GB_EMIT
  }
}

// ---------------------------------------------------------------------------
// K4: 64-step scan, one workgroup per q. gbase precomputed; 7 barriers/step;
// ping-pong prefetch of next step's task/gbase/mask rows; redundant per-wave
// rt reduce and per-thread qos-scalar state (registers).
// ---------------------------------------------------------------------------
__global__ __launch_bounds__(256, 4)
void scan_kernel(const float* __restrict__ tasks, const int* __restrict__ masks,
                 const int* __restrict__ topologicals,
                 const float* __restrict__ w_node1,
                 const float* __restrict__ w_ser1,
                 const float* __restrict__ b_ser1,
                 const float* __restrict__ gbase,
                 const float* __restrict__ Mbuf, const float* __restrict__ dvec,
                 const unsigned* __restrict__ keys, float* __restrict__ out) {
  const int q = blockIdx.x, tid = threadIdx.x;
  const int lane = tid & 127, half = tid >> 7;
  const int wl = tid & 63;  // lane within wave

  __shared__ float task_s[2][TASKW];
  __shared__ float gb_s[2][128];
  __shared__ int mask_s[2][128];
  __shared__ int topo_s[64];
  __shared__ float sg[128];
  __shared__ float4 wst4[128];  // w_ser1 transposed: (w0,w1,w2,w3) per h
  __shared__ float2 hp[128];    // per-step pack: (b_ser1[h], uu[h])
  __shared__ float logit_s[128];
  __shared__ float gl[128];
  __shared__ float red[256];
  __shared__ float qos_s[64 * 4];
  __shared__ float ridx_s[64], rprob_s[64];
  __shared__ float qw[4][128];  // w_node1 rows 128..131 (qos features)
  __shared__ float dvs[128];
  __shared__ float scal[2];  // 0:mx 1:sumexp
  __shared__ int sidx_s;
  __shared__ unsigned keys_s[128];

  float Mr[64];
#pragma unroll
  for (int j = 0; j < 64; ++j) Mr[j] = Mbuf[(half * 64 + j) * 128 + lane];

  if (tid < 64) topo_s[tid] = topologicals[q * 64 + tid];
  if (tid < 128) {
    wst4[tid] = make_float4(w_ser1[tid], w_ser1[128 + tid], w_ser1[256 + tid],
                            w_ser1[384 + tid]);
    dvs[tid] = dvec[tid];
    keys_s[tid] = keys[tid];
  }
  for (int i = tid; i < 512; i += 256)
    qw[i >> 7][i & 127] = w_node1[(128 + (i >> 7)) * 128 + (i & 127)];
  if (tid < 64) {
    qos_s[tid * 4 + 0] = 3.0f;
    qos_s[tid * 4 + 1] = 1.0f;
    qos_s[tid * 4 + 2] = 0.0f;
    qos_s[tid * 4 + 3] = 1.0f;
    ridx_s[tid] = 0.0f;
    rprob_s[tid] = 0.0f;
  }
  const float bsl = b_ser1[lane];
  float ava = 1.0f, tp = 3.0f, rel = 1.0f;  // per-thread redundant state
  __syncthreads();

  // Prologue: stage step 0 into buffer 0
  {
    const int topo0 = topo_s[63];
    if (tid < 144)
      ((float4*)task_s[0])[tid] =
          ((const float4*)(tasks + (size_t)(q * 64 + topo0) * TASKW))[tid];
    if (tid < 128) {
      gb_s[0][tid] = gbase[(q * 64 + topo0) * 128 + tid];
      mask_s[0][tid] = masks[(q * 64 + topo0) * 128 + tid];
    }
  }
  __syncthreads();

  for (int t = 0; t < 64; ++t) {
    const int cur = t & 1, nxt = cur ^ 1;
    const int topo = topo_s[63 - t];

    // rt reduce, redundantly in every wave (no cross-wave broadcast needed)
    float rt;
    {
      float p = task_s[cur][wl] * qos_s[wl * 4];
#pragma unroll
      for (int o = 32; o > 0; o >>= 1) p = fmaxf(p, __shfl_xor(p, o, 64));
      rt = p;
    }
    // sg = fsilu(gbase + qos-part)
    if (tid < 128) {
      float g = gb_s[cur][tid];
      g = fmaf(rt, qw[0][tid], g);
      g = fmaf(ava, qw[1][tid], g);
      g = fmaf(tp, qw[2][tid], g);
      g = fmaf(rel, qw[3][tid], g);
      sg[tid] = fsilu(g);
    }
    __syncthreads();  // B_a

    // u = silu(g) @ M + dvec (split partials)
    {
      float acc = 0.0f;
      const float2* sg2 = (const float2*)sg + half * 32;
#pragma unroll
      for (int j = 0; j < 32; ++j) {
        const float2 x = sg2[j];
        acc = fmaf(x.x, Mr[2 * j], acc);
        acc = fmaf(x.y, Mr[2 * j + 1], acc);
      }
      red[tid] = acc;
    }
    __syncthreads();  // B_b
    if (tid < 128) {
      const float uu = red[tid] + red[tid + 128] + dvs[tid];
      hp[tid] = make_float2(bsl, uu);
    }
    __syncthreads();  // B_c

    // Prefetch next step's rows (issue before logits compute; lands in regs)
    float4 pf_task;
    float pf_gb;
    int pf_mask;
    {
      const int tn = (t < 63) ? t + 1 : 63;
      const int ntopo = topo_s[63 - tn];
      if (tid < 144)
        pf_task =
            ((const float4*)(tasks + (size_t)(q * 64 + ntopo) * TASKW))[tid];
      if (tid < 128) {
        pf_gb = gbase[(q * 64 + ntopo) * 128 + tid];
        pf_mask = masks[(q * 64 + ntopo) * 128 + tid];
      }
    }

    // logits[s] partial over h-half: 2 LDS + ~9 VALU per h
    {
      const float4 sv = *(const float4*)&task_s[cur][64 + 4 * lane];
      float acc = 0.0f;
      const int hb = half * 64;
#pragma unroll 16
      for (int j = 0; j < 64; ++j) {
        const int h = hb + j;
        const float4 w = wst4[h];
        const float2 hb2 = hp[h];
        float h1 = fmaf(sv.x, w.x, hb2.x);
        h1 = fmaf(sv.y, w.y, h1);
        h1 = fmaf(sv.z, w.z, h1);
        h1 = fmaf(sv.w, w.w, h1);
        const float e = __builtin_amdgcn_exp2f(h1 * -1.44269504088896f);
        const float r = __builtin_amdgcn_rcpf(1.0f + e);
        acc = fmaf(h1 * r, hb2.y, acc);
      }
      red[tid] = acc;
    }
    __syncthreads();  // B_d

    // logits finish + gumbel; also write prefetched rows to the other buffer
    if (tid < 128) {
      float l = red[tid] + red[tid + 128];
      if (mask_s[cur][tid] == 0) l = NEGV;
      logit_s[tid] = l;
      unsigned o0, o1;
      threefry2x32(keys_s[2 * t], keys_s[2 * t + 1], 0u,
                   (unsigned)(q * 128 + tid), o0, o1);
      const unsigned bits = o0 ^ o1;
      const float f = __uint_as_float((bits >> 9) | 0x3f800000u) - 1.0f;
      const float u = (f > 0.0f) ? f : 1.17549435e-38f;
      const float gmb = -flog(-flog(u));
      gl[tid] = l + gmb;
    }
    if (tid < 144) ((float4*)task_s[nxt])[tid] = pf_task;
    if (tid < 128) {
      gb_s[nxt][tid] = pf_gb;
      mask_s[nxt][tid] = pf_mask;
    }
    __syncthreads();  // B_e

    // wave0: argmax(gl); wave1: mx + sumexp
    if (tid < 64) {
      float z = gl[tid];
      int zi = tid;
      const float z2 = gl[tid + 64];
      if (z2 > z) { z = z2; zi = tid + 64; }
#pragma unroll
      for (int o = 32; o > 0; o >>= 1) {
        const float zo = __shfl_xor(z, o, 64);
        const int io = __shfl_xor(zi, o, 64);
        if (zo > z || (zo == z && io < zi)) { z = zo; zi = io; }
      }
      if (tid == 0) sidx_s = zi;
    } else if (tid < 128) {
      const int l2 = tid - 64;
      const float la = logit_s[l2], lb = logit_s[l2 + 64];
      float mx = fmaxf(la, lb);
#pragma unroll
      for (int o = 32; o > 0; o >>= 1) mx = fmaxf(mx, __shfl_xor(mx, o, 64));
      float e = fexp(la - mx) + fexp(lb - mx);
#pragma unroll
      for (int o = 32; o > 0; o >>= 1) e += __shfl_xor(e, o, 64);
      if (l2 == 0) { scal[0] = mx; scal[1] = e; }
    }
    __syncthreads();  // B_f

    // State update: every thread redundantly (keeps ava/tp/rel in registers)
    {
      const int si = sidx_s;
      const float s1v = task_s[cur][64 + 4 * si + 1];
      const float s2v = task_s[cur][64 + 4 * si + 2];
      const float s3v = task_s[cur][64 + 4 * si + 3];
      if (tid == 0) {
        const float s0v = task_s[cur][64 + 4 * si];
        const float prob = fexp(logit_s[si] - scal[0]) / scal[1];
        qos_s[topo * 4 + 0] = s0v + rt;
        qos_s[topo * 4 + 1] = s1v * ava;
        qos_s[topo * 4 + 2] = fminf(s2v, tp);
        qos_s[topo * 4 + 3] = s3v * rel;
        ridx_s[topo] += (float)si;
        rprob_s[topo] += prob;
      }
      ava = s1v * ava;
      tp = fminf(s2v, tp);
      rel = s3v * rel;
    }
    __syncthreads();  // B_final
  }
  if (tid < 64) {
    out[q * 64 + tid] = ridx_s[tid];
    out[Qn * Nn + q * 64 + tid] = rprob_s[tid];
  }
}

// ---------------------------------------------------------------------------
extern "C" void kernel_launch(void* const* d_in, const int* in_sizes, int n_in,
                              void* d_out, int out_size, void* d_ws,
                              size_t ws_size, hipStream_t stream) {
  const float* tasks = (const float*)d_in[0];
  const float* constraints = (const float*)d_in[1];
  const int* masks = (const int*)d_in[2];
  const int* topologicals = (const int*)d_in[3];
  const float* w_init1 = (const float*)d_in[4];
  const float* b_init1 = (const float*)d_in[5];
  const float* w_init2 = (const float*)d_in[6];
  const float* b_init2 = (const float*)d_in[7];
  const float* wq = (const float*)d_in[8];
  const float* bq = (const float*)d_in[9];
  const float* wk = (const float*)d_in[10];
  const float* bk = (const float*)d_in[11];
  const float* wv = (const float*)d_in[12];
  const float* bv = (const float*)d_in[13];
  const float* wo = (const float*)d_in[14];
  const float* bo = (const float*)d_in[15];
  const float* w_node1 = (const float*)d_in[16];
  const float* b_node1 = (const float*)d_in[17];
  const float* w_node2 = (const float*)d_in[18];
  const float* b_node2 = (const float*)d_in[19];
  const float* w_ser1 = (const float*)d_in[20];
  const float* b_ser1 = (const float*)d_in[21];
  const float* w_ser2 = (const float*)d_in[22];
  const float* b_ser2 = (const float*)d_in[23];

  float* ws = (float*)d_ws;
  float* node_emb = ws;                                // Q*N*E; later: gbase
  float* nodes_emb = node_emb + (size_t)Qn * Nn * En;  // Q*N*E (y, then final)
  float* Mbuf = nodes_emb + (size_t)Qn * Nn * En;      // 128*128
  float* dvec = Mbuf + 128 * 128;
  unsigned* keys = (unsigned*)(dvec + 128);            // 128 u32
  float* gbase = node_emb;  // reuse: node_emb dead after gbase_kernel input

  setup_kernel<<<130, 128, 0, stream>>>(w_node2, b_node2, w_ser2, b_ser2, Mbuf,
                                        dvec, keys);
  init_mlp_kernel<<<Qn, 256, 0, stream>>>(tasks, constraints, w_init1, b_init1,
                                          w_init2, b_init2, node_emb);
  mha_kernel<<<Qn, 256, 0, stream>>>(node_emb, wq, bq, wk, bk, wv, bv,
                                     nodes_emb);
  outproj_kernel<<<Qn, 256, 0, stream>>>(node_emb, wo, bo, nodes_emb);
  gbase_kernel<<<Qn, 256, 0, stream>>>(nodes_emb, w_node1, b_node1, gbase);
  scan_kernel<<<Qn, 256, 0, stream>>>(tasks, masks, topologicals, w_node1,
                                      w_ser1, b_ser1, gbase, Mbuf, dvec, keys,
                                      (float*)d_out);
}